// Round 1
// baseline (1669.355 us; speedup 1.0000x reference)
//
#include <hip/hip_runtime.h>
#include <hip/hip_bf16.h>

// DynamicSequenceChunker: B=8, L=4096, D=1024, DK=1024
// out = [downsampled (8*4096*1024) | chunk_lens (8*4096) | weighted_aux_loss (1)], fp32
//
// Pipeline:
//  0) memset ws accumulators (dot, qn2, ksn2)
//  1) gemm_cos: fp32 tiled GEMM over (q|k) column pairs; epilogue reduces
//     per-row dot/qn2/ksn2 partials via atomics; stores tile-boundary q/k rows
//  2) boundary_fix: dot/ksn2 for rows t ≡ 0 (mod 128) using stored rows or start_key
//  3) chunk_scan: probs, boundary mask, block prefix-sum compaction, chunk_lens, aux_b
//  4) aux_final: scalar loss
//  5) gather: downsampled = tokens[bpos] * probs[bpos] (zeros for invalid)

#define B_ 8
#define L_ 4096
#define D_ 1024
#define M_TOT (B_ * L_)          // 32768
#define BM 128
#define BK 32
#define NTILES_M (M_TOT / BM)    // 256
#define NTILES_N (D_ / 64)       // 16
#define DS_ELEMS ((size_t)M_TOT * D_)   // 33554432

// ---------------- ws layout (float elements) ----------------
// dot     [32768]      @ 0
// qn2     [32768]      @ 32768
// ksn2    [32768]      @ 65536
// probs   [32768]      @ 98304
// bpos    [32768] int  @ 131072
// nc      [8]    int   @ 163840
// aux     [8]          @ 163856
// qrow    [256*1024]   @ 163872
// krow    [256*1024]   @ 426016   (end 688160 floats = 2.75 MB)

__global__ __launch_bounds__(256, 2)
void gemm_cos(const float* __restrict__ A,    // tokens [32768,1024]
              const float* __restrict__ W,    // W_qk   [1024,2048]
              float* __restrict__ dotw, float* __restrict__ qn2w,
              float* __restrict__ ksn2w,
              float* __restrict__ qrow, float* __restrict__ krow)
{
    __shared__ float smem[17408];            // 69.6 KB
    float* As = smem;                         // [32][132], row stride 132 (528B, 16B-aligned)
    float* Bs = smem + 32 * 132;              // [32][132]

    const int tile_n = blockIdx.x;            // 0..15
    const int tile_m = blockIdx.y;            // 0..255
    const int m0 = tile_m * BM;
    const int n0 = tile_n * 64;
    const int tid = threadIdx.x;
    const int tx = tid & 15;                  // column group
    const int ty = tid >> 4;                  // row group (rows ty*8..ty*8+7)

    float acc_q[8][4] = {};
    float acc_k[8][4] = {};

    for (int kt = 0; kt < D_; kt += BK) {
        // A tile: 128 rows x 32 k; seg = m*8 + k8 (k8: 16B chunk)
        #pragma unroll
        for (int i = 0; i < 4; ++i) {
            int seg = tid + 256 * i;
            int m = seg >> 3, k8 = seg & 7;
            float4 v = *reinterpret_cast<const float4*>(
                A + (size_t)(m0 + m) * D_ + kt + k8 * 4);
            As[(k8 * 4 + 0) * 132 + m] = v.x;
            As[(k8 * 4 + 1) * 132 + m] = v.y;
            As[(k8 * 4 + 2) * 132 + m] = v.z;
            As[(k8 * 4 + 3) * 132 + m] = v.w;
        }
        // B tile: 32 k x (64 q-cols | 64 k-cols); seg = k*32 + half*16 + f4
        #pragma unroll
        for (int i = 0; i < 4; ++i) {
            int seg = tid + 256 * i;
            int k = seg >> 5, rest = seg & 31, half = rest >> 4, f4 = rest & 15;
            float4 v = *reinterpret_cast<const float4*>(
                W + (size_t)(kt + k) * 2048 + half * 1024 + n0 + f4 * 4);
            *reinterpret_cast<float4*>(&Bs[k * 132 + half * 64 + f4 * 4]) = v;
        }
        __syncthreads();

        #pragma unroll 8
        for (int k = 0; k < BK; ++k) {
            float a0[4], a1[4], bq[4], bk[4];
            *(float4*)a0 = *(float4*)&As[k * 132 + ty * 8];
            *(float4*)a1 = *(float4*)&As[k * 132 + ty * 8 + 4];
            *(float4*)bq = *(float4*)&Bs[k * 132 + tx * 4];
            *(float4*)bk = *(float4*)&Bs[k * 132 + 64 + tx * 4];
            #pragma unroll
            for (int i = 0; i < 4; ++i) {
                #pragma unroll
                for (int j = 0; j < 4; ++j) {
                    acc_q[i][j]     += a0[i] * bq[j];
                    acc_q[4 + i][j] += a1[i] * bq[j];
                    acc_k[i][j]     += a0[i] * bk[j];
                    acc_k[4 + i][j] += a1[i] * bk[j];
                }
            }
        }
        __syncthreads();
    }

    // ---- epilogue: tiles -> LDS, per-row partials -> atomics ----
    float* Q  = smem;                // [128][68], row stride 68 (272B, 16B-aligned)
    float* Kl = smem + 128 * 68;

    #pragma unroll
    for (int i = 0; i < 8; ++i) {
        *(float4*)&Q [(ty * 8 + i) * 68 + tx * 4] =
            make_float4(acc_q[i][0], acc_q[i][1], acc_q[i][2], acc_q[i][3]);
        *(float4*)&Kl[(ty * 8 + i) * 68 + tx * 4] =
            make_float4(acc_k[i][0], acc_k[i][1], acc_k[i][2], acc_k[i][3]);
    }
    __syncthreads();

    // 2 threads per row, 32 cols each
    const int r = tid >> 1, h = tid & 1;
    float q2 = 0.f, d = 0.f, k2 = 0.f;
    #pragma unroll
    for (int c = 0; c < 32; c += 4) {
        float4 qv = *(float4*)&Q[r * 68 + h * 32 + c];
        q2 += qv.x * qv.x + qv.y * qv.y + qv.z * qv.z + qv.w * qv.w;
    }
    if (r >= 1) {
        #pragma unroll
        for (int c = 0; c < 32; c += 4) {
            float4 qv = *(float4*)&Q [r * 68 + h * 32 + c];
            float4 kv = *(float4*)&Kl[(r - 1) * 68 + h * 32 + c];
            d  += qv.x * kv.x + qv.y * kv.y + qv.z * kv.z + qv.w * kv.w;
            k2 += kv.x * kv.x + kv.y * kv.y + kv.z * kv.z + kv.w * kv.w;
        }
    }
    q2 += __shfl_down(q2, 1, 64);
    d  += __shfl_down(d,  1, 64);
    k2 += __shfl_down(k2, 1, 64);
    if (h == 0) {
        const int m = m0 + r;
        atomicAdd(&qn2w[m], q2);
        if (r >= 1) { atomicAdd(&dotw[m], d); atomicAdd(&ksn2w[m], k2); }
    }
    // boundary row slices
    if (tid < 16)
        *(float4*)&qrow[(size_t)tile_m * D_ + n0 + tid * 4] = *(float4*)&Q[0 * 68 + tid * 4];
    else if (tid < 32) {
        int t2 = tid - 16;
        *(float4*)&krow[(size_t)tile_m * D_ + n0 + t2 * 4] = *(float4*)&Kl[127 * 68 + t2 * 4];
    }
}

__global__ __launch_bounds__(256)
void boundary_fix(const float* __restrict__ qrow, const float* __restrict__ krow,
                  const float* __restrict__ start_key,
                  float* __restrict__ dotw, float* __restrict__ ksn2w)
{
    const int tile = blockIdx.x;                 // 0..255
    const int m = tile * BM;
    const int tid = threadIdx.x;
    const float* q  = qrow + (size_t)tile * D_;
    const float* ks = ((tile & 31) == 0) ? start_key : (krow + (size_t)(tile - 1) * D_);

    float4 qv = *(const float4*)&q[tid * 4];
    float4 kv = *(const float4*)&ks[tid * 4];
    float d  = qv.x * kv.x + qv.y * kv.y + qv.z * kv.z + qv.w * kv.w;
    float k2 = kv.x * kv.x + kv.y * kv.y + kv.z * kv.z + kv.w * kv.w;

    #pragma unroll
    for (int off = 32; off; off >>= 1) {
        d  += __shfl_down(d, off, 64);
        k2 += __shfl_down(k2, off, 64);
    }
    __shared__ float sd[4], sk[4];
    const int lane = tid & 63, wid = tid >> 6;
    if (lane == 0) { sd[wid] = d; sk[wid] = k2; }
    __syncthreads();
    if (tid == 0) {
        dotw[m]  = sd[0] + sd[1] + sd[2] + sd[3];
        ksn2w[m] = sk[0] + sk[1] + sk[2] + sk[3];
    }
}

__global__ __launch_bounds__(1024)
void chunk_scan(const float* __restrict__ dotw, const float* __restrict__ qn2w,
                const float* __restrict__ ksn2w, float* __restrict__ probsw,
                int* __restrict__ bposw, int* __restrict__ ncw,
                float* __restrict__ auxw, float* __restrict__ out_lens)
{
    const int b = blockIdx.x, tid = threadIdx.x;
    const int lane = tid & 63, wid = tid >> 6;
    __shared__ int wcnt[16];
    __shared__ float wsum[16];
    __shared__ int s_nc;
    __shared__ float s_ps;

    const int base = b * L_ + tid * 4;
    float4 dv = *(const float4*)&dotw[base];
    float4 qv = *(const float4*)&qn2w[base];
    float4 kv = *(const float4*)&ksn2w[base];
    const float ds4[4] = {dv.x, dv.y, dv.z, dv.w};
    const float qs4[4] = {qv.x, qv.y, qv.z, qv.w};
    const float ks4[4] = {kv.x, kv.y, kv.z, kv.w};

    float p[4]; bool mk[4]; int cnt = 0; float psum = 0.f;
    #pragma unroll
    for (int j = 0; j < 4; ++j) {
        float qn = fmaxf(sqrtf(qs4[j]), 1e-8f);
        float kn = fmaxf(sqrtf(ks4[j]), 1e-8f);
        p[j] = 0.5f * (1.f - ds4[j] / (qn * kn));
        mk[j] = (p[j] > 0.5f) || ((tid * 4 + j) == 0);
        cnt += mk[j] ? 1 : 0;
        psum += p[j];
    }
    *(float4*)&probsw[base] = make_float4(p[0], p[1], p[2], p[3]);

    int inc = cnt;
    #pragma unroll
    for (int off = 1; off < 64; off <<= 1) {
        int n = __shfl_up(inc, off, 64);
        if (lane >= off) inc += n;
    }
    float ps = psum;
    #pragma unroll
    for (int off = 32; off; off >>= 1) ps += __shfl_down(ps, off, 64);
    if (lane == 63) wcnt[wid] = inc;
    if (lane == 0)  wsum[wid] = ps;
    __syncthreads();
    if (tid == 0) {
        int run = 0; float t = 0.f;
        for (int i = 0; i < 16; ++i) { int c = wcnt[i]; wcnt[i] = run; run += c; t += wsum[i]; }
        s_nc = run; s_ps = t;
    }
    __syncthreads();
    const int nc = s_nc;
    int idx = wcnt[wid] + (inc - cnt);
    #pragma unroll
    for (int j = 0; j < 4; ++j)
        if (mk[j]) { bposw[b * L_ + idx] = tid * 4 + j; ++idx; }
    if (tid == 0) {
        ncw[b] = nc;
        float G  = s_ps * (1.f / L_);
        float Fm = (float)nc * (1.f / L_);
        auxw[b] = 1.2f * (5.f * Fm * G + (1.f - Fm) * (1.f - G));
    }
    __syncthreads();   // bposw visible block-wide
    #pragma unroll
    for (int j = 0; j < 4; ++j) {
        int i = tid * 4 + j;
        float len = 0.f;
        if (i < nc) {
            int pi  = bposw[b * L_ + i];
            int nxt = (i + 1 < nc) ? bposw[b * L_ + i + 1] : L_;
            len = (float)(nxt - pi);
        }
        out_lens[b * L_ + i] = len;
    }
}

__global__ void aux_final(const float* __restrict__ auxw, float* __restrict__ out_scalar)
{
    if (threadIdx.x == 0) {
        float s = 0.f;
        for (int i = 0; i < B_; ++i) s += auxw[i];
        *out_scalar = 0.03f * (s * (1.f / B_));
    }
}

__global__ __launch_bounds__(256)
void gather_ds(const float* __restrict__ tokens, const float* __restrict__ probsw,
               const int* __restrict__ bposw, const int* __restrict__ ncw,
               float* __restrict__ out)
{
    const int row = blockIdx.x;          // 0..32767 output rows
    const int b = row >> 12, i = row & 4095;
    const int nc = ncw[b];
    float4 v = make_float4(0.f, 0.f, 0.f, 0.f);
    if (i < nc) {
        const int t = bposw[b * L_ + i];
        const float pv = probsw[b * L_ + t];
        float4 tv = *(const float4*)&tokens[((size_t)(b << 12) + t) * D_ + threadIdx.x * 4];
        v = make_float4(tv.x * pv, tv.y * pv, tv.z * pv, tv.w * pv);
    }
    *(float4*)&out[(size_t)row * D_ + threadIdx.x * 4] = v;
}

extern "C" void kernel_launch(void* const* d_in, const int* in_sizes, int n_in,
                              void* d_out, int out_size, void* d_ws, size_t ws_size,
                              hipStream_t stream)
{
    const float* tokens    = (const float*)d_in[0];
    const float* W_qk      = (const float*)d_in[1];
    const float* start_key = (const float*)d_in[2];
    float* out = (float*)d_out;

    float* wf   = (float*)d_ws;
    float* dotw  = wf;
    float* qn2w  = wf + 32768;
    float* ksn2w = wf + 65536;
    float* probsw = wf + 98304;
    int*   bposw  = (int*)(wf + 131072);
    int*   ncw    = (int*)(wf + 163840);
    float* auxw   = wf + 163856;
    float* qrow   = wf + 163872;
    float* krow   = wf + 426016;

    // zero the atomic accumulators (dot, qn2, ksn2)
    hipMemsetAsync(d_ws, 0, (size_t)3 * M_TOT * sizeof(float), stream);

    gemm_cos<<<dim3(NTILES_N, NTILES_M), 256, 0, stream>>>(
        tokens, W_qk, dotw, qn2w, ksn2w, qrow, krow);

    boundary_fix<<<NTILES_M, 256, 0, stream>>>(qrow, krow, start_key, dotw, ksn2w);

    chunk_scan<<<B_, 1024, 0, stream>>>(dotw, qn2w, ksn2w, probsw, bposw, ncw, auxw,
                                        out + DS_ELEMS);

    aux_final<<<1, 64, 0, stream>>>(auxw, out + DS_ELEMS + M_TOT);

    gather_ds<<<M_TOT, 256, 0, stream>>>(tokens, probsw, bposw, ncw, out);
}

// Round 2
// 943.919 us; speedup vs baseline: 1.7685x; 1.7685x over previous
//
#include <hip/hip_runtime.h>
#include <hip/hip_bf16.h>

// DynamicSequenceChunker: B=8, L=4096, D=1024, DK=1024
// Fast path: split-bf16 3-GEMM on MFMA (AhiBhi + AhiBlo + AloBhi, fp32 acc)
//            + fp32 fixup of near-threshold rows (|cos| < 1e-4).
// Fallback (ws too small): round-1 fp32 vector GEMM path.

#define B_ 8
#define L_ 4096
#define D_ 1024
#define M_TOT (B_ * L_)          // 32768
#define BM 128
#define DS_ELEMS ((size_t)M_TOT * D_)   // 33554432

typedef __bf16 bf16x8 __attribute__((ext_vector_type(8)));
typedef __bf16 bf16x4 __attribute__((ext_vector_type(4)));
typedef float  f32x4  __attribute__((ext_vector_type(4)));

typedef __attribute__((address_space(1))) void gv_t;
typedef __attribute__((address_space(3))) void lv_t;

__device__ __forceinline__ void gl_lds16(const void* g, void* l) {
    __builtin_amdgcn_global_load_lds((gv_t*)g, (lv_t*)l, 16, 0, 0);
}

// ---------------------------------------------------------------------------
// split kernels
// ---------------------------------------------------------------------------
__global__ __launch_bounds__(256)
void split_tokens(const float* __restrict__ x, __bf16* __restrict__ hi,
                  __bf16* __restrict__ lo)
{
    const int idx = (blockIdx.x * 256 + threadIdx.x) * 4;
    float4 v = *(const float4*)&x[idx];
    float vs[4] = {v.x, v.y, v.z, v.w};
    bf16x4 h, l;
    #pragma unroll
    for (int j = 0; j < 4; ++j) {
        __bf16 hh = (__bf16)vs[j];
        h[j] = hh;
        l[j] = (__bf16)(vs[j] - (float)hh);
    }
    *(bf16x4*)&hi[idx] = h;
    *(bf16x4*)&lo[idx] = l;
}

// W [1024 k][2048 n] -> wT_hi/wT_lo [2048 n][1024 k] bf16 (split)
__global__ __launch_bounds__(256)
void split_wT(const float* __restrict__ W, __bf16* __restrict__ wT_hi,
              __bf16* __restrict__ wT_lo)
{
    __shared__ __bf16 lh[32 * 33], ll[32 * 33];
    const int k0 = blockIdx.x * 32;       // 0..31 tiles
    const int n0 = blockIdx.y * 32;       // 0..63 tiles
    const int t = threadIdx.x;
    {
        const int lk = t >> 3, ln4 = (t & 7) * 4;
        float4 v = *(const float4*)&W[(size_t)(k0 + lk) * 2048 + n0 + ln4];
        float vs[4] = {v.x, v.y, v.z, v.w};
        #pragma unroll
        for (int j = 0; j < 4; ++j) {
            __bf16 hh = (__bf16)vs[j];
            lh[(ln4 + j) * 33 + lk] = hh;
            ll[(ln4 + j) * 33 + lk] = (__bf16)(vs[j] - (float)hh);
        }
    }
    __syncthreads();
    {
        const int ln = t >> 3, lk4 = (t & 7) * 4;
        bf16x4 h, l;
        #pragma unroll
        for (int j = 0; j < 4; ++j) {
            h[j] = lh[ln * 33 + lk4 + j];
            l[j] = ll[ln * 33 + lk4 + j];
        }
        *(bf16x4*)&wT_hi[(size_t)(n0 + ln) * 1024 + k0 + lk4] = h;
        *(bf16x4*)&wT_lo[(size_t)(n0 + ln) * 1024 + k0 + lk4] = l;
    }
}

// ---------------------------------------------------------------------------
// MFMA GEMM: tile 128 rows x (64 q-cols + 64 k-cols); grid (16, 256)
// K-loop: 3 slabs (hi*hi, hi*lo, lo*hi) x 32 steps of BK=32
// ---------------------------------------------------------------------------
__global__ __launch_bounds__(256, 2)
void gemm_cos_mfma(const __bf16* __restrict__ t_hi, const __bf16* __restrict__ t_lo,
                   const __bf16* __restrict__ wT_hi, const __bf16* __restrict__ wT_lo,
                   float* __restrict__ dotw, float* __restrict__ qn2w,
                   float* __restrict__ ksn2w,
                   float* __restrict__ qrow, float* __restrict__ krow)
{
    __shared__ float smem[8448];                    // 33792 B
    __bf16* As = (__bf16*)smem;                     // [128 m][32 k]
    __bf16* Bs = (__bf16*)smem + 4096;              // [128 n][32 k] (0..63 q, 64..127 k)
    float*  Ck = smem;                              // epilogue [128][66]

    const int tile_n = blockIdx.x;                  // 0..15
    const int tile_m = blockIdx.y;                  // 0..255
    const int m0 = tile_m * BM;
    const int n0 = tile_n * 64;
    const int tid  = threadIdx.x;
    const int w    = tid >> 6;
    const int lane = tid & 63;
    const int quad = lane >> 4;
    const int lc   = lane & 15;

    const int wm  = (w & 1) * 64;                   // row half
    const int wq0 = (w >> 1) * 32;                  // q/k col quarter

    // staging geometry: 8 A-insts + 8 B-insts of 1KB; wave w does ia/ib = 2w, 2w+1
    const int ia0 = w * 2, ia1 = w * 2 + 1;
    const size_t a_g0 = (size_t)(m0 + ia0 * 16 + (lane >> 2)) * 1024 + (lane & 3) * 8;
    const size_t a_g1 = a_g0 + (size_t)16 * 1024;
    const int br0 = ia0 * 16 + (lane >> 2);
    const int br1 = br0 + 16;
    const int gr0 = (br0 < 64) ? (n0 + br0) : (960 + n0 + br0);
    const int gr1 = (br1 < 64) ? (n0 + br1) : (960 + n0 + br1);
    const size_t b_g0 = (size_t)gr0 * 1024 + (lane & 3) * 8;
    const size_t b_g1 = (size_t)gr1 * 1024 + (lane & 3) * 8;
    char* aL0 = (char*)smem + ia0 * 1024;
    char* aL1 = (char*)smem + ia1 * 1024;
    char* bL0 = (char*)smem + 8192 + ia0 * 1024;
    char* bL1 = (char*)smem + 8192 + ia1 * 1024;

    f32x4 accq[4][2] = {};
    f32x4 acck[4][2] = {};

    for (int kk = 0; kk < 96; ++kk) {
        const int slab = kk >> 5;
        const size_t kb = (size_t)(kk & 31) * 32;
        const __bf16* Ap = (slab < 2) ? t_hi : t_lo;
        const __bf16* Bp = (slab == 1) ? wT_lo : wT_hi;

        gl_lds16(Ap + a_g0 + kb, aL0);
        gl_lds16(Ap + a_g1 + kb, aL1);
        gl_lds16(Bp + b_g0 + kb, bL0);
        gl_lds16(Bp + b_g1 + kb, bL1);
        __syncthreads();

        bf16x8 af[4], bq[2], bk[2];
        #pragma unroll
        for (int mi = 0; mi < 4; ++mi)
            af[mi] = *(const bf16x8*)(As + (wm + mi * 16 + lc) * 32 + quad * 8);
        #pragma unroll
        for (int ni = 0; ni < 2; ++ni) {
            bq[ni] = *(const bf16x8*)(Bs + (wq0 + ni * 16 + lc) * 32 + quad * 8);
            bk[ni] = *(const bf16x8*)(Bs + (64 + wq0 + ni * 16 + lc) * 32 + quad * 8);
        }
        #pragma unroll
        for (int mi = 0; mi < 4; ++mi) {
            #pragma unroll
            for (int ni = 0; ni < 2; ++ni) {
                accq[mi][ni] = __builtin_amdgcn_mfma_f32_16x16x32_bf16(
                    af[mi], bq[ni], accq[mi][ni], 0, 0, 0);
                acck[mi][ni] = __builtin_amdgcn_mfma_f32_16x16x32_bf16(
                    af[mi], bk[ni], acck[mi][ni], 0, 0, 0);
            }
        }
        __syncthreads();
    }

    // ---- epilogue ----
    // qn2 (row = wm + mi*16 + quad*4 + reg), reduce 16 lanes of the quad
    #pragma unroll
    for (int mi = 0; mi < 4; ++mi) {
        #pragma unroll
        for (int reg = 0; reg < 4; ++reg) {
            const int row = wm + mi * 16 + quad * 4 + reg;
            float s = accq[mi][0][reg] * accq[mi][0][reg]
                    + accq[mi][1][reg] * accq[mi][1][reg];
            s += __shfl_xor(s, 1); s += __shfl_xor(s, 2);
            s += __shfl_xor(s, 4); s += __shfl_xor(s, 8);
            if (lc == 0) atomicAdd(&qn2w[m0 + row], s);

            float s2 = acck[mi][0][reg] * acck[mi][0][reg]
                     + acck[mi][1][reg] * acck[mi][1][reg];
            s2 += __shfl_xor(s2, 1); s2 += __shfl_xor(s2, 2);
            s2 += __shfl_xor(s2, 4); s2 += __shfl_xor(s2, 8);
            if (lc == 0 && row < 127) atomicAdd(&ksn2w[m0 + row + 1], s2);
        }
    }

    // Ck tile -> LDS for the r-1 shift
    #pragma unroll
    for (int mi = 0; mi < 4; ++mi)
        #pragma unroll
        for (int ni = 0; ni < 2; ++ni)
            #pragma unroll
            for (int reg = 0; reg < 4; ++reg)
                Ck[(wm + mi * 16 + quad * 4 + reg) * 66 + wq0 + ni * 16 + lc] =
                    acck[mi][ni][reg];
    __syncthreads();

    #pragma unroll
    for (int mi = 0; mi < 4; ++mi) {
        #pragma unroll
        for (int reg = 0; reg < 4; ++reg) {
            const int row = wm + mi * 16 + quad * 4 + reg;
            float d = 0.f;
            if (row >= 1)
                d = accq[mi][0][reg] * Ck[(row - 1) * 66 + wq0 + lc]
                  + accq[mi][1][reg] * Ck[(row - 1) * 66 + wq0 + 16 + lc];
            d += __shfl_xor(d, 1); d += __shfl_xor(d, 2);
            d += __shfl_xor(d, 4); d += __shfl_xor(d, 8);
            if (lc == 0 && row >= 1) atomicAdd(&dotw[m0 + row], d);
        }
    }

    // boundary row slices (fp32) for boundary_fix
    if (wm == 0 && quad == 0) {
        #pragma unroll
        for (int ni = 0; ni < 2; ++ni)
            qrow[(size_t)tile_m * D_ + n0 + wq0 + ni * 16 + lc] = accq[0][ni][0];
    }
    if (wm == 64 && quad == 3) {
        #pragma unroll
        for (int ni = 0; ni < 2; ++ni)
            krow[(size_t)tile_m * D_ + n0 + wq0 + ni * 16 + lc] = acck[3][ni][3];
    }
}

// ---------------------------------------------------------------------------
__global__ __launch_bounds__(256)
void boundary_fix(const float* __restrict__ qrow, const float* __restrict__ krow,
                  const float* __restrict__ start_key,
                  float* __restrict__ dotw, float* __restrict__ ksn2w)
{
    const int tile = blockIdx.x;                 // 0..255
    const int m = tile * BM;
    const int tid = threadIdx.x;
    const float* q  = qrow + (size_t)tile * D_;
    const float* ks = ((tile & 31) == 0) ? start_key : (krow + (size_t)(tile - 1) * D_);

    float4 qv = *(const float4*)&q[tid * 4];
    float4 kv = *(const float4*)&ks[tid * 4];
    float d  = qv.x * kv.x + qv.y * kv.y + qv.z * kv.z + qv.w * kv.w;
    float k2 = kv.x * kv.x + kv.y * kv.y + kv.z * kv.z + kv.w * kv.w;

    #pragma unroll
    for (int off = 32; off; off >>= 1) {
        d  += __shfl_down(d, off, 64);
        k2 += __shfl_down(k2, off, 64);
    }
    __shared__ float sd[4], sk[4];
    const int lane = tid & 63, wid = tid >> 6;
    if (lane == 0) { sd[wid] = d; sk[wid] = k2; }
    __syncthreads();
    if (tid == 0) {
        dotw[m]  = sd[0] + sd[1] + sd[2] + sd[3];
        ksn2w[m] = sk[0] + sk[1] + sk[2] + sk[3];
    }
}

// probs for all rows + suspect list (|cos| < 1e-4)
__global__ __launch_bounds__(256)
void probs_suspects(const float* __restrict__ dotw, const float* __restrict__ qn2w,
                    const float* __restrict__ ksn2w, float* __restrict__ probsw,
                    int* __restrict__ scount, int* __restrict__ slist)
{
    const int m = blockIdx.x * 256 + threadIdx.x;
    float qn = fmaxf(sqrtf(qn2w[m]), 1e-8f);
    float kn = fmaxf(sqrtf(ksn2w[m]), 1e-8f);
    float c = dotw[m] / (qn * kn);
    probsw[m] = 0.5f * (1.f - c);
    if (fabsf(c) < 1e-4f) {
        int i = atomicAdd(scount, 1);
        if (i < 4096) slist[i] = m;
    }
}

// exact fp32 recompute of suspect rows
__global__ __launch_bounds__(256)
void fixup(const float* __restrict__ tokens, const float* __restrict__ W,
           const float* __restrict__ start_key, const int* __restrict__ scount,
           const int* __restrict__ slist, float* __restrict__ probsw)
{
    __shared__ float ta[1024], tb[1024];
    __shared__ float rq[4], rk[4], rd[4];
    const int tid = threadIdx.x;
    int n = *scount; if (n > 4096) n = 4096;

    for (int i = blockIdx.x; i < n; i += gridDim.x) {
        const int t = slist[i];
        const bool st = (t & 4095) == 0;
        *(float4*)&ta[tid * 4] = *(const float4*)&tokens[(size_t)t * 1024 + tid * 4];
        if (!st)
            *(float4*)&tb[tid * 4] = *(const float4*)&tokens[(size_t)(t - 1) * 1024 + tid * 4];
        __syncthreads();

        float q[4] = {0, 0, 0, 0}, kv[4] = {0, 0, 0, 0};
        if (st) {
            for (int k = 0; k < 1024; ++k) {
                float a = ta[k];
                float4 wq = *(const float4*)&W[(size_t)k * 2048 + tid * 4];
                q[0] = fmaf(a, wq.x, q[0]); q[1] = fmaf(a, wq.y, q[1]);
                q[2] = fmaf(a, wq.z, q[2]); q[3] = fmaf(a, wq.w, q[3]);
            }
            float4 sv = *(const float4*)&start_key[tid * 4];
            kv[0] = sv.x; kv[1] = sv.y; kv[2] = sv.z; kv[3] = sv.w;
        } else {
            for (int k = 0; k < 1024; ++k) {
                float a = ta[k], b = tb[k];
                float4 wq = *(const float4*)&W[(size_t)k * 2048 + tid * 4];
                float4 wk = *(const float4*)&W[(size_t)k * 2048 + 1024 + tid * 4];
                q[0] = fmaf(a, wq.x, q[0]); q[1] = fmaf(a, wq.y, q[1]);
                q[2] = fmaf(a, wq.z, q[2]); q[3] = fmaf(a, wq.w, q[3]);
                kv[0] = fmaf(b, wk.x, kv[0]); kv[1] = fmaf(b, wk.y, kv[1]);
                kv[2] = fmaf(b, wk.z, kv[2]); kv[3] = fmaf(b, wk.w, kv[3]);
            }
        }
        float q2 = 0, k2 = 0, dd = 0;
        #pragma unroll
        for (int j = 0; j < 4; ++j) {
            q2 += q[j] * q[j]; k2 += kv[j] * kv[j]; dd += q[j] * kv[j];
        }
        #pragma unroll
        for (int off = 32; off; off >>= 1) {
            q2 += __shfl_down(q2, off, 64);
            k2 += __shfl_down(k2, off, 64);
            dd += __shfl_down(dd, off, 64);
        }
        const int lane = tid & 63, wid = tid >> 6;
        if (lane == 0) { rq[wid] = q2; rk[wid] = k2; rd[wid] = dd; }
        __syncthreads();
        if (tid == 0) {
            float Q2 = rq[0] + rq[1] + rq[2] + rq[3];
            float K2 = rk[0] + rk[1] + rk[2] + rk[3];
            float DD = rd[0] + rd[1] + rd[2] + rd[3];
            float qn = fmaxf(sqrtf(Q2), 1e-8f), kn = fmaxf(sqrtf(K2), 1e-8f);
            probsw[t] = 0.5f * (1.f - DD / (qn * kn));
        }
        __syncthreads();
    }
}

// chunk scan reading precomputed probs
__global__ __launch_bounds__(1024)
void chunk_scan_p(const float* __restrict__ probsw, int* __restrict__ bposw,
                  int* __restrict__ ncw, float* __restrict__ auxw,
                  float* __restrict__ out_lens)
{
    const int b = blockIdx.x, tid = threadIdx.x;
    const int lane = tid & 63, wid = tid >> 6;
    __shared__ int wcnt[16];
    __shared__ float wsum[16];
    __shared__ int s_nc;
    __shared__ float s_ps;

    const int base = b * L_ + tid * 4;
    float4 pv = *(const float4*)&probsw[base];
    const float p[4] = {pv.x, pv.y, pv.z, pv.w};

    bool mk[4]; int cnt = 0; float psum = 0.f;
    #pragma unroll
    for (int j = 0; j < 4; ++j) {
        mk[j] = (p[j] > 0.5f) || ((tid * 4 + j) == 0);
        cnt += mk[j] ? 1 : 0;
        psum += p[j];
    }
    int inc = cnt;
    #pragma unroll
    for (int off = 1; off < 64; off <<= 1) {
        int nn = __shfl_up(inc, off, 64);
        if (lane >= off) inc += nn;
    }
    float ps = psum;
    #pragma unroll
    for (int off = 32; off; off >>= 1) ps += __shfl_down(ps, off, 64);
    if (lane == 63) wcnt[wid] = inc;
    if (lane == 0)  wsum[wid] = ps;
    __syncthreads();
    if (tid == 0) {
        int run = 0; float tt = 0.f;
        for (int i = 0; i < 16; ++i) { int c = wcnt[i]; wcnt[i] = run; run += c; tt += wsum[i]; }
        s_nc = run; s_ps = tt;
    }
    __syncthreads();
    const int nc = s_nc;
    int idx = wcnt[wid] + (inc - cnt);
    #pragma unroll
    for (int j = 0; j < 4; ++j)
        if (mk[j]) { bposw[b * L_ + idx] = tid * 4 + j; ++idx; }
    if (tid == 0) {
        ncw[b] = nc;
        float G  = s_ps * (1.f / L_);
        float Fm = (float)nc * (1.f / L_);
        auxw[b] = 1.2f * (5.f * Fm * G + (1.f - Fm) * (1.f - G));
    }
    __syncthreads();
    #pragma unroll
    for (int j = 0; j < 4; ++j) {
        int i = tid * 4 + j;
        float len = 0.f;
        if (i < nc) {
            int pi  = bposw[b * L_ + i];
            int nxt = (i + 1 < nc) ? bposw[b * L_ + i + 1] : L_;
            len = (float)(nxt - pi);
        }
        out_lens[b * L_ + i] = len;
    }
}

__global__ void aux_final(const float* __restrict__ auxw, float* __restrict__ out_scalar)
{
    if (threadIdx.x == 0) {
        float s = 0.f;
        for (int i = 0; i < B_; ++i) s += auxw[i];
        *out_scalar = 0.03f * (s * (1.f / B_));
    }
}

__global__ __launch_bounds__(256)
void gather_ds(const float* __restrict__ tokens, const float* __restrict__ probsw,
               const int* __restrict__ bposw, const int* __restrict__ ncw,
               float* __restrict__ out)
{
    const int row = blockIdx.x;
    const int b = row >> 12, i = row & 4095;
    const int nc = ncw[b];
    float4 v = make_float4(0.f, 0.f, 0.f, 0.f);
    if (i < nc) {
        const int t = bposw[b * L_ + i];
        const float pv = probsw[b * L_ + t];
        float4 tv = *(const float4*)&tokens[((size_t)(b << 12) + t) * D_ + threadIdx.x * 4];
        v = make_float4(tv.x * pv, tv.y * pv, tv.z * pv, tv.w * pv);
    }
    *(float4*)&out[(size_t)row * D_ + threadIdx.x * 4] = v;
}

// ===========================================================================
// Round-1 fallback kernels (fp32 vector GEMM) — used if ws_size is too small
// ===========================================================================
__global__ __launch_bounds__(256, 2)
void gemm_cos(const float* __restrict__ A, const float* __restrict__ W,
              float* __restrict__ dotw, float* __restrict__ qn2w,
              float* __restrict__ ksn2w,
              float* __restrict__ qrow, float* __restrict__ krow)
{
    __shared__ float smem[17408];
    float* As = smem;
    float* Bs = smem + 32 * 132;

    const int tile_n = blockIdx.x;
    const int tile_m = blockIdx.y;
    const int m0 = tile_m * BM;
    const int n0 = tile_n * 64;
    const int tid = threadIdx.x;
    const int tx = tid & 15;
    const int ty = tid >> 4;

    float acc_q[8][4] = {};
    float acc_k[8][4] = {};

    for (int kt = 0; kt < D_; kt += 32) {
        #pragma unroll
        for (int i = 0; i < 4; ++i) {
            int seg = tid + 256 * i;
            int m = seg >> 3, k8 = seg & 7;
            float4 v = *reinterpret_cast<const float4*>(
                A + (size_t)(m0 + m) * D_ + kt + k8 * 4);
            As[(k8 * 4 + 0) * 132 + m] = v.x;
            As[(k8 * 4 + 1) * 132 + m] = v.y;
            As[(k8 * 4 + 2) * 132 + m] = v.z;
            As[(k8 * 4 + 3) * 132 + m] = v.w;
        }
        #pragma unroll
        for (int i = 0; i < 4; ++i) {
            int seg = tid + 256 * i;
            int k = seg >> 5, rest = seg & 31, half = rest >> 4, f4 = rest & 15;
            float4 v = *reinterpret_cast<const float4*>(
                W + (size_t)(kt + k) * 2048 + half * 1024 + n0 + f4 * 4);
            *reinterpret_cast<float4*>(&Bs[k * 132 + half * 64 + f4 * 4]) = v;
        }
        __syncthreads();
        #pragma unroll 8
        for (int k = 0; k < 32; ++k) {
            float a0[4], a1[4], bq[4], bk[4];
            *(float4*)a0 = *(float4*)&As[k * 132 + ty * 8];
            *(float4*)a1 = *(float4*)&As[k * 132 + ty * 8 + 4];
            *(float4*)bq = *(float4*)&Bs[k * 132 + tx * 4];
            *(float4*)bk = *(float4*)&Bs[k * 132 + 64 + tx * 4];
            #pragma unroll
            for (int i = 0; i < 4; ++i)
                #pragma unroll
                for (int j = 0; j < 4; ++j) {
                    acc_q[i][j]     += a0[i] * bq[j];
                    acc_q[4 + i][j] += a1[i] * bq[j];
                    acc_k[i][j]     += a0[i] * bk[j];
                    acc_k[4 + i][j] += a1[i] * bk[j];
                }
        }
        __syncthreads();
    }

    float* Q  = smem;
    float* Kl = smem + 128 * 68;
    #pragma unroll
    for (int i = 0; i < 8; ++i) {
        *(float4*)&Q [(ty * 8 + i) * 68 + tx * 4] =
            make_float4(acc_q[i][0], acc_q[i][1], acc_q[i][2], acc_q[i][3]);
        *(float4*)&Kl[(ty * 8 + i) * 68 + tx * 4] =
            make_float4(acc_k[i][0], acc_k[i][1], acc_k[i][2], acc_k[i][3]);
    }
    __syncthreads();

    const int r = tid >> 1, h = tid & 1;
    float q2 = 0.f, d = 0.f, k2 = 0.f;
    #pragma unroll
    for (int c = 0; c < 32; c += 4) {
        float4 qv = *(float4*)&Q[r * 68 + h * 32 + c];
        q2 += qv.x * qv.x + qv.y * qv.y + qv.z * qv.z + qv.w * qv.w;
    }
    if (r >= 1) {
        #pragma unroll
        for (int c = 0; c < 32; c += 4) {
            float4 qv = *(float4*)&Q [r * 68 + h * 32 + c];
            float4 kv = *(float4*)&Kl[(r - 1) * 68 + h * 32 + c];
            d  += qv.x * kv.x + qv.y * kv.y + qv.z * kv.z + qv.w * kv.w;
            k2 += kv.x * kv.x + kv.y * kv.y + kv.z * kv.z + kv.w * kv.w;
        }
    }
    q2 += __shfl_down(q2, 1, 64);
    d  += __shfl_down(d,  1, 64);
    k2 += __shfl_down(k2, 1, 64);
    if (h == 0) {
        const int m = m0 + r;
        atomicAdd(&qn2w[m], q2);
        if (r >= 1) { atomicAdd(&dotw[m], d); atomicAdd(&ksn2w[m], k2); }
    }
    if (tid < 16)
        *(float4*)&qrow[(size_t)tile_m * D_ + n0 + tid * 4] = *(float4*)&Q[0 * 68 + tid * 4];
    else if (tid < 32) {
        int t2 = tid - 16;
        *(float4*)&krow[(size_t)tile_m * D_ + n0 + t2 * 4] = *(float4*)&Kl[127 * 68 + t2 * 4];
    }
}

__global__ __launch_bounds__(1024)
void chunk_scan(const float* __restrict__ dotw, const float* __restrict__ qn2w,
                const float* __restrict__ ksn2w, float* __restrict__ probsw,
                int* __restrict__ bposw, int* __restrict__ ncw,
                float* __restrict__ auxw, float* __restrict__ out_lens)
{
    const int b = blockIdx.x, tid = threadIdx.x;
    const int lane = tid & 63, wid = tid >> 6;
    __shared__ int wcnt[16];
    __shared__ float wsum[16];
    __shared__ int s_nc;
    __shared__ float s_ps;

    const int base = b * L_ + tid * 4;
    float4 dv = *(const float4*)&dotw[base];
    float4 qv = *(const float4*)&qn2w[base];
    float4 kv = *(const float4*)&ksn2w[base];
    const float ds4[4] = {dv.x, dv.y, dv.z, dv.w};
    const float qs4[4] = {qv.x, qv.y, qv.z, qv.w};
    const float ks4[4] = {kv.x, kv.y, kv.z, kv.w};

    float p[4]; bool mk[4]; int cnt = 0; float psum = 0.f;
    #pragma unroll
    for (int j = 0; j < 4; ++j) {
        float qn = fmaxf(sqrtf(qs4[j]), 1e-8f);
        float kn = fmaxf(sqrtf(ks4[j]), 1e-8f);
        p[j] = 0.5f * (1.f - ds4[j] / (qn * kn));
        mk[j] = (p[j] > 0.5f) || ((tid * 4 + j) == 0);
        cnt += mk[j] ? 1 : 0;
        psum += p[j];
    }
    *(float4*)&probsw[base] = make_float4(p[0], p[1], p[2], p[3]);

    int inc = cnt;
    #pragma unroll
    for (int off = 1; off < 64; off <<= 1) {
        int nn = __shfl_up(inc, off, 64);
        if (lane >= off) inc += nn;
    }
    float ps = psum;
    #pragma unroll
    for (int off = 32; off; off >>= 1) ps += __shfl_down(ps, off, 64);
    if (lane == 63) wcnt[wid] = inc;
    if (lane == 0)  wsum[wid] = ps;
    __syncthreads();
    if (tid == 0) {
        int run = 0; float t = 0.f;
        for (int i = 0; i < 16; ++i) { int c = wcnt[i]; wcnt[i] = run; run += c; t += wsum[i]; }
        s_nc = run; s_ps = t;
    }
    __syncthreads();
    const int nc = s_nc;
    int idx = wcnt[wid] + (inc - cnt);
    #pragma unroll
    for (int j = 0; j < 4; ++j)
        if (mk[j]) { bposw[b * L_ + idx] = tid * 4 + j; ++idx; }
    if (tid == 0) {
        ncw[b] = nc;
        float G  = s_ps * (1.f / L_);
        float Fm = (float)nc * (1.f / L_);
        auxw[b] = 1.2f * (5.f * Fm * G + (1.f - Fm) * (1.f - G));
    }
    __syncthreads();
    #pragma unroll
    for (int j = 0; j < 4; ++j) {
        int i = tid * 4 + j;
        float len = 0.f;
        if (i < nc) {
            int pi  = bposw[b * L_ + i];
            int nxt = (i + 1 < nc) ? bposw[b * L_ + i + 1] : L_;
            len = (float)(nxt - pi);
        }
        out_lens[b * L_ + i] = len;
    }
}

// ===========================================================================
extern "C" void kernel_launch(void* const* d_in, const int* in_sizes, int n_in,
                              void* d_out, int out_size, void* d_ws, size_t ws_size,
                              hipStream_t stream)
{
    const float* tokens    = (const float*)d_in[0];
    const float* W_qk      = (const float*)d_in[1];
    const float* start_key = (const float*)d_in[2];
    float* out = (float*)d_out;
    float* lens_out = out + DS_ELEMS;
    float* aux_out  = out + DS_ELEMS + M_TOT;

    const size_t need_fast = (size_t)2789396 * 4;   // ~11.2 MB

    if (ws_size >= need_fast) {
        float* wf = (float*)d_ws;
        float* dotw   = wf;                  // 32768
        float* qn2w   = wf + 32768;          // 32768
        float* ksn2w  = wf + 65536;          // 32768
        int*   scount = (int*)(wf + 98304);  // 1
        float* probsw = wf + 98308;          // 32768
        int*   bposw  = (int*)(wf + 131076); // 32768
        int*   ncw    = (int*)(wf + 163844); // 8
        float* auxw   = wf + 163852;         // 8
        int*   slist  = (int*)(wf + 163860); // 4096
        float* qrow   = wf + 167956;         // 262144
        float* krow   = wf + 430100;         // 262144
        __bf16* wT_hi = (__bf16*)(wf + 692244);   // 2097152 bf16
        __bf16* wT_lo = (__bf16*)(wf + 1740820);  // 2097152 bf16
        // bf16 token splits live in d_out's downsampled region (overwritten later)
        __bf16* t_hi = (__bf16*)out;                     // 33554432 bf16 = 16777216 f
        __bf16* t_lo = (__bf16*)(out + 16777216);

        hipMemsetAsync(d_ws, 0, 393220, stream);   // dot/qn2/ksn2 + scount

        split_tokens<<<32768, 256, 0, stream>>>(tokens, t_hi, t_lo);
        split_wT<<<dim3(32, 64), 256, 0, stream>>>(W_qk, wT_hi, wT_lo);

        gemm_cos_mfma<<<dim3(16, 256), 256, 0, stream>>>(
            t_hi, t_lo, wT_hi, wT_lo, dotw, qn2w, ksn2w, qrow, krow);

        boundary_fix<<<256, 256, 0, stream>>>(qrow, krow, start_key, dotw, ksn2w);
        probs_suspects<<<128, 256, 0, stream>>>(dotw, qn2w, ksn2w, probsw, scount, slist);
        fixup<<<128, 256, 0, stream>>>(tokens, W_qk, start_key, scount, slist, probsw);
        chunk_scan_p<<<B_, 1024, 0, stream>>>(probsw, bposw, ncw, auxw, lens_out);
        aux_final<<<1, 64, 0, stream>>>(auxw, aux_out);
        gather_ds<<<M_TOT, 256, 0, stream>>>(tokens, probsw, bposw, ncw, out);
    } else {
        // round-1 fp32 fallback
        float* wf = (float*)d_ws;
        float* dotw   = wf;
        float* qn2w   = wf + 32768;
        float* ksn2w  = wf + 65536;
        float* probsw = wf + 98304;
        int*   bposw  = (int*)(wf + 131072);
        int*   ncw    = (int*)(wf + 163840);
        float* auxw   = wf + 163856;
        float* qrow   = wf + 163872;
        float* krow   = wf + 426016;

        hipMemsetAsync(d_ws, 0, (size_t)3 * M_TOT * sizeof(float), stream);
        gemm_cos<<<dim3(16, 256), 256, 0, stream>>>(
            tokens, W_qk, dotw, qn2w, ksn2w, qrow, krow);
        boundary_fix<<<256, 256, 0, stream>>>(qrow, krow, start_key, dotw, ksn2w);
        chunk_scan<<<B_, 1024, 0, stream>>>(dotw, qn2w, ksn2w, probsw, bposw, ncw,
                                            auxw, lens_out);
        aux_final<<<1, 64, 0, stream>>>(auxw, aux_out);
        gather_ds<<<M_TOT, 256, 0, stream>>>(tokens, probsw, bposw, ncw, out);
    }
}

// Round 3
// 936.946 us; speedup vs baseline: 1.7817x; 1.0074x over previous
//
#include <hip/hip_runtime.h>
#include <hip/hip_bf16.h>

// DynamicSequenceChunker: B=8, L=4096, D=1024, DK=1024
// Fast path: split-bf16 3-GEMM on MFMA (AhiBhi + AhiBlo + AloBhi, fp32 acc)
//            + fp32 fixup of near-threshold rows (|cos| < 1e-4).
// R3: XOR bank-conflict swizzle in GEMM LDS tiles; fused boundary+probs;
//     aux folded into chunk_scan (atomic).

#define B_ 8
#define L_ 4096
#define D_ 1024
#define M_TOT (B_ * L_)          // 32768
#define BM 128
#define DS_ELEMS ((size_t)M_TOT * D_)   // 33554432

typedef __bf16 bf16x8 __attribute__((ext_vector_type(8)));
typedef __bf16 bf16x4 __attribute__((ext_vector_type(4)));
typedef float  f32x4  __attribute__((ext_vector_type(4)));

typedef __attribute__((address_space(1))) void gv_t;
typedef __attribute__((address_space(3))) void lv_t;

__device__ __forceinline__ void gl_lds16(const void* g, void* l) {
    __builtin_amdgcn_global_load_lds((gv_t*)g, (lv_t*)l, 16, 0, 0);
}

// ---------------------------------------------------------------------------
// split kernels
// ---------------------------------------------------------------------------
__global__ __launch_bounds__(256)
void split_tokens(const float* __restrict__ x, __bf16* __restrict__ hi,
                  __bf16* __restrict__ lo)
{
    const int idx = (blockIdx.x * 256 + threadIdx.x) * 4;
    float4 v = *(const float4*)&x[idx];
    float vs[4] = {v.x, v.y, v.z, v.w};
    bf16x4 h, l;
    #pragma unroll
    for (int j = 0; j < 4; ++j) {
        __bf16 hh = (__bf16)vs[j];
        h[j] = hh;
        l[j] = (__bf16)(vs[j] - (float)hh);
    }
    *(bf16x4*)&hi[idx] = h;
    *(bf16x4*)&lo[idx] = l;
}

// W [1024 k][2048 n] -> wT_hi/wT_lo [2048 n][1024 k] bf16 (split)
__global__ __launch_bounds__(256)
void split_wT(const float* __restrict__ W, __bf16* __restrict__ wT_hi,
              __bf16* __restrict__ wT_lo)
{
    __shared__ __bf16 lh[32 * 33], ll[32 * 33];
    const int k0 = blockIdx.x * 32;
    const int n0 = blockIdx.y * 32;
    const int t = threadIdx.x;
    {
        const int lk = t >> 3, ln4 = (t & 7) * 4;
        float4 v = *(const float4*)&W[(size_t)(k0 + lk) * 2048 + n0 + ln4];
        float vs[4] = {v.x, v.y, v.z, v.w};
        #pragma unroll
        for (int j = 0; j < 4; ++j) {
            __bf16 hh = (__bf16)vs[j];
            lh[(ln4 + j) * 33 + lk] = hh;
            ll[(ln4 + j) * 33 + lk] = (__bf16)(vs[j] - (float)hh);
        }
    }
    __syncthreads();
    {
        const int ln = t >> 3, lk4 = (t & 7) * 4;
        bf16x4 h, l;
        #pragma unroll
        for (int j = 0; j < 4; ++j) {
            h[j] = lh[ln * 33 + lk4 + j];
            l[j] = ll[ln * 33 + lk4 + j];
        }
        *(bf16x4*)&wT_hi[(size_t)(n0 + ln) * 1024 + k0 + lk4] = h;
        *(bf16x4*)&wT_lo[(size_t)(n0 + ln) * 1024 + k0 + lk4] = l;
    }
}

// ---------------------------------------------------------------------------
// MFMA GEMM: tile 128 rows x (64 q-cols + 64 k-cols); grid (16, 256)
// K-loop: 3 slabs (hi*hi, hi*lo, lo*hi) x 32 steps of BK=32
// LDS k-chunk XOR swizzle: LDS[r][c] = G[r][c ^ ((r&15)>>1 & 3)]
// ---------------------------------------------------------------------------
__global__ __launch_bounds__(256, 2)
void gemm_cos_mfma(const __bf16* __restrict__ t_hi, const __bf16* __restrict__ t_lo,
                   const __bf16* __restrict__ wT_hi, const __bf16* __restrict__ wT_lo,
                   float* __restrict__ dotw, float* __restrict__ qn2w,
                   float* __restrict__ ksn2w,
                   float* __restrict__ qrow, float* __restrict__ krow)
{
    __shared__ float smem[8448];                    // 33792 B
    __bf16* As = (__bf16*)smem;                     // [128 m][32 k] swizzled
    __bf16* Bs = (__bf16*)smem + 4096;              // [128 n][32 k] swizzled
    float*  Ck = smem;                              // epilogue [128][66]

    const int tile_n = blockIdx.x;                  // 0..15
    const int tile_m = blockIdx.y;                  // 0..255
    const int m0 = tile_m * BM;
    const int n0 = tile_n * 64;
    const int tid  = threadIdx.x;
    const int w    = tid >> 6;
    const int lane = tid & 63;
    const int quad = lane >> 4;
    const int lc   = lane & 15;

    const int wm  = (w & 1) * 64;                   // row half
    const int wq0 = (w >> 1) * 32;                  // q/k col quarter

    // staging: 8 A + 8 B insts of 1KB; wave w does ia = 2w, 2w+1
    // global chunk swizzle: chunk = (lane&3) ^ ((lane>>3)&3)
    const int ia0 = w * 2, ia1 = w * 2 + 1;
    const int st_ch = (((lane & 3) ^ ((lane >> 3) & 3))) * 8;   // element offset
    const size_t a_g0 = (size_t)(m0 + ia0 * 16 + (lane >> 2)) * 1024 + st_ch;
    const size_t a_g1 = a_g0 + (size_t)16 * 1024;
    const int br0 = ia0 * 16 + (lane >> 2);
    const int br1 = br0 + 16;
    const int gr0 = (br0 < 64) ? (n0 + br0) : (960 + n0 + br0);
    const int gr1 = (br1 < 64) ? (n0 + br1) : (960 + n0 + br1);
    const size_t b_g0 = (size_t)gr0 * 1024 + st_ch;
    const size_t b_g1 = (size_t)gr1 * 1024 + st_ch;
    char* aL0 = (char*)smem + ia0 * 1024;
    char* aL1 = (char*)smem + ia1 * 1024;
    char* bL0 = (char*)smem + 8192 + ia0 * 1024;
    char* bL1 = (char*)smem + 8192 + ia1 * 1024;

    // fragment-read swizzle: chunk = quad ^ ((lc>>1)&3)
    const int fr_ch = ((quad ^ ((lc >> 1) & 3))) * 8;

    f32x4 accq[4][2] = {};
    f32x4 acck[4][2] = {};

    for (int kk = 0; kk < 96; ++kk) {
        const int slab = kk >> 5;
        const size_t kb = (size_t)(kk & 31) * 32;
        const __bf16* Ap = (slab < 2) ? t_hi : t_lo;
        const __bf16* Bp = (slab == 1) ? wT_lo : wT_hi;

        gl_lds16(Ap + a_g0 + kb, aL0);
        gl_lds16(Ap + a_g1 + kb, aL1);
        gl_lds16(Bp + b_g0 + kb, bL0);
        gl_lds16(Bp + b_g1 + kb, bL1);
        __syncthreads();

        bf16x8 af[4], bq[2], bk[2];
        #pragma unroll
        for (int mi = 0; mi < 4; ++mi)
            af[mi] = *(const bf16x8*)(As + (wm + mi * 16 + lc) * 32 + fr_ch);
        #pragma unroll
        for (int ni = 0; ni < 2; ++ni) {
            bq[ni] = *(const bf16x8*)(Bs + (wq0 + ni * 16 + lc) * 32 + fr_ch);
            bk[ni] = *(const bf16x8*)(Bs + (64 + wq0 + ni * 16 + lc) * 32 + fr_ch);
        }
        #pragma unroll
        for (int mi = 0; mi < 4; ++mi) {
            #pragma unroll
            for (int ni = 0; ni < 2; ++ni) {
                accq[mi][ni] = __builtin_amdgcn_mfma_f32_16x16x32_bf16(
                    af[mi], bq[ni], accq[mi][ni], 0, 0, 0);
                acck[mi][ni] = __builtin_amdgcn_mfma_f32_16x16x32_bf16(
                    af[mi], bk[ni], acck[mi][ni], 0, 0, 0);
            }
        }
        __syncthreads();
    }

    // ---- epilogue ----
    #pragma unroll
    for (int mi = 0; mi < 4; ++mi) {
        #pragma unroll
        for (int reg = 0; reg < 4; ++reg) {
            const int row = wm + mi * 16 + quad * 4 + reg;
            float s = accq[mi][0][reg] * accq[mi][0][reg]
                    + accq[mi][1][reg] * accq[mi][1][reg];
            s += __shfl_xor(s, 1); s += __shfl_xor(s, 2);
            s += __shfl_xor(s, 4); s += __shfl_xor(s, 8);
            if (lc == 0) atomicAdd(&qn2w[m0 + row], s);

            float s2 = acck[mi][0][reg] * acck[mi][0][reg]
                     + acck[mi][1][reg] * acck[mi][1][reg];
            s2 += __shfl_xor(s2, 1); s2 += __shfl_xor(s2, 2);
            s2 += __shfl_xor(s2, 4); s2 += __shfl_xor(s2, 8);
            if (lc == 0 && row < 127) atomicAdd(&ksn2w[m0 + row + 1], s2);
        }
    }

    #pragma unroll
    for (int mi = 0; mi < 4; ++mi)
        #pragma unroll
        for (int ni = 0; ni < 2; ++ni)
            #pragma unroll
            for (int reg = 0; reg < 4; ++reg)
                Ck[(wm + mi * 16 + quad * 4 + reg) * 66 + wq0 + ni * 16 + lc] =
                    acck[mi][ni][reg];
    __syncthreads();

    #pragma unroll
    for (int mi = 0; mi < 4; ++mi) {
        #pragma unroll
        for (int reg = 0; reg < 4; ++reg) {
            const int row = wm + mi * 16 + quad * 4 + reg;
            float d = 0.f;
            if (row >= 1)
                d = accq[mi][0][reg] * Ck[(row - 1) * 66 + wq0 + lc]
                  + accq[mi][1][reg] * Ck[(row - 1) * 66 + wq0 + 16 + lc];
            d += __shfl_xor(d, 1); d += __shfl_xor(d, 2);
            d += __shfl_xor(d, 4); d += __shfl_xor(d, 8);
            if (lc == 0 && row >= 1) atomicAdd(&dotw[m0 + row], d);
        }
    }

    if (wm == 0 && quad == 0) {
        #pragma unroll
        for (int ni = 0; ni < 2; ++ni)
            qrow[(size_t)tile_m * D_ + n0 + wq0 + ni * 16 + lc] = accq[0][ni][0];
    }
    if (wm == 64 && quad == 3) {
        #pragma unroll
        for (int ni = 0; ni < 2; ++ni)
            krow[(size_t)tile_m * D_ + n0 + wq0 + ni * 16 + lc] = acck[3][ni][3];
    }
}

// ---------------------------------------------------------------------------
// fused: boundary dot (row t ≡ 0 mod 128) + probs + suspect list
// ---------------------------------------------------------------------------
__global__ __launch_bounds__(256)
void probs_fused(const float* __restrict__ qrow, const float* __restrict__ krow,
                 const float* __restrict__ start_key,
                 const float* __restrict__ dotw, const float* __restrict__ qn2w,
                 const float* __restrict__ ksn2w, float* __restrict__ probsw,
                 int* __restrict__ scount, int* __restrict__ slist)
{
    const int tile = blockIdx.x;                 // 0..255
    const int tid = threadIdx.x;
    __shared__ float sd[4], sk[4];

    // phase 1: fp32 dot/ksn2 for the tile's first row
    {
        const float* q  = qrow + (size_t)tile * D_;
        const float* ks = ((tile & 31) == 0) ? start_key
                                             : (krow + (size_t)(tile - 1) * D_);
        float4 qv = *(const float4*)&q[tid * 4];
        float4 kv = *(const float4*)&ks[tid * 4];
        float d  = qv.x * kv.x + qv.y * kv.y + qv.z * kv.z + qv.w * kv.w;
        float k2 = kv.x * kv.x + kv.y * kv.y + kv.z * kv.z + kv.w * kv.w;
        #pragma unroll
        for (int off = 32; off; off >>= 1) {
            d  += __shfl_down(d, off, 64);
            k2 += __shfl_down(k2, off, 64);
        }
        const int lane = tid & 63, wid = tid >> 6;
        if (lane == 0) { sd[wid] = d; sk[wid] = k2; }
    }
    __syncthreads();

    // phase 2: probs for the 128 rows
    if (tid < BM) {
        const int m = tile * BM + tid;
        float dd = dotw[m], kk = ksn2w[m];
        if (tid == 0) {
            dd = sd[0] + sd[1] + sd[2] + sd[3];
            kk = sk[0] + sk[1] + sk[2] + sk[3];
        }
        float qn = fmaxf(sqrtf(qn2w[m]), 1e-8f);
        float kn = fmaxf(sqrtf(kk), 1e-8f);
        float c = dd / (qn * kn);
        probsw[m] = 0.5f * (1.f - c);
        if (fabsf(c) < 1e-4f) {
            int i = atomicAdd(scount, 1);
            if (i < 4096) slist[i] = m;
        }
    }
}

// exact fp32 recompute of suspect rows
__global__ __launch_bounds__(256)
void fixup(const float* __restrict__ tokens, const float* __restrict__ W,
           const float* __restrict__ start_key, const int* __restrict__ scount,
           const int* __restrict__ slist, float* __restrict__ probsw)
{
    __shared__ float ta[1024], tb[1024];
    __shared__ float rq[4], rk[4], rd[4];
    const int tid = threadIdx.x;
    int n = *scount; if (n > 4096) n = 4096;

    for (int i = blockIdx.x; i < n; i += gridDim.x) {
        const int t = slist[i];
        const bool st = (t & 4095) == 0;
        *(float4*)&ta[tid * 4] = *(const float4*)&tokens[(size_t)t * 1024 + tid * 4];
        if (!st)
            *(float4*)&tb[tid * 4] = *(const float4*)&tokens[(size_t)(t - 1) * 1024 + tid * 4];
        __syncthreads();

        float q[4] = {0, 0, 0, 0}, kv[4] = {0, 0, 0, 0};
        if (st) {
            #pragma unroll 4
            for (int k = 0; k < 1024; ++k) {
                float a = ta[k];
                float4 wq = *(const float4*)&W[(size_t)k * 2048 + tid * 4];
                q[0] = fmaf(a, wq.x, q[0]); q[1] = fmaf(a, wq.y, q[1]);
                q[2] = fmaf(a, wq.z, q[2]); q[3] = fmaf(a, wq.w, q[3]);
            }
            float4 sv = *(const float4*)&start_key[tid * 4];
            kv[0] = sv.x; kv[1] = sv.y; kv[2] = sv.z; kv[3] = sv.w;
        } else {
            #pragma unroll 4
            for (int k = 0; k < 1024; ++k) {
                float a = ta[k], b = tb[k];
                float4 wq = *(const float4*)&W[(size_t)k * 2048 + tid * 4];
                float4 wk = *(const float4*)&W[(size_t)k * 2048 + 1024 + tid * 4];
                q[0] = fmaf(a, wq.x, q[0]); q[1] = fmaf(a, wq.y, q[1]);
                q[2] = fmaf(a, wq.z, q[2]); q[3] = fmaf(a, wq.w, q[3]);
                kv[0] = fmaf(b, wk.x, kv[0]); kv[1] = fmaf(b, wk.y, kv[1]);
                kv[2] = fmaf(b, wk.z, kv[2]); kv[3] = fmaf(b, wk.w, kv[3]);
            }
        }
        float q2 = 0, k2 = 0, dd = 0;
        #pragma unroll
        for (int j = 0; j < 4; ++j) {
            q2 += q[j] * q[j]; k2 += kv[j] * kv[j]; dd += q[j] * kv[j];
        }
        #pragma unroll
        for (int off = 32; off; off >>= 1) {
            q2 += __shfl_down(q2, off, 64);
            k2 += __shfl_down(k2, off, 64);
            dd += __shfl_down(dd, off, 64);
        }
        const int lane = tid & 63, wid = tid >> 6;
        if (lane == 0) { rq[wid] = q2; rk[wid] = k2; rd[wid] = dd; }
        __syncthreads();
        if (tid == 0) {
            float Q2 = rq[0] + rq[1] + rq[2] + rq[3];
            float K2 = rk[0] + rk[1] + rk[2] + rk[3];
            float DD = rd[0] + rd[1] + rd[2] + rd[3];
            float qn = fmaxf(sqrtf(Q2), 1e-8f), kn = fmaxf(sqrtf(K2), 1e-8f);
            probsw[t] = 0.5f * (1.f - DD / (qn * kn));
        }
        __syncthreads();
    }
}

// chunk scan reading precomputed probs; aux accumulated atomically into out
__global__ __launch_bounds__(1024)
void chunk_scan_p(const float* __restrict__ probsw, int* __restrict__ bposw,
                  int* __restrict__ ncw, float* __restrict__ aux_out,
                  float* __restrict__ out_lens)
{
    const int b = blockIdx.x, tid = threadIdx.x;
    const int lane = tid & 63, wid = tid >> 6;
    __shared__ int wcnt[16];
    __shared__ float wsum[16];
    __shared__ int s_nc;
    __shared__ float s_ps;

    const int base = b * L_ + tid * 4;
    float4 pv = *(const float4*)&probsw[base];
    const float p[4] = {pv.x, pv.y, pv.z, pv.w};

    bool mk[4]; int cnt = 0; float psum = 0.f;
    #pragma unroll
    for (int j = 0; j < 4; ++j) {
        mk[j] = (p[j] > 0.5f) || ((tid * 4 + j) == 0);
        cnt += mk[j] ? 1 : 0;
        psum += p[j];
    }
    int inc = cnt;
    #pragma unroll
    for (int off = 1; off < 64; off <<= 1) {
        int nn = __shfl_up(inc, off, 64);
        if (lane >= off) inc += nn;
    }
    float ps = psum;
    #pragma unroll
    for (int off = 32; off; off >>= 1) ps += __shfl_down(ps, off, 64);
    if (lane == 63) wcnt[wid] = inc;
    if (lane == 0)  wsum[wid] = ps;
    __syncthreads();
    if (tid == 0) {
        int run = 0; float tt = 0.f;
        for (int i = 0; i < 16; ++i) { int c = wcnt[i]; wcnt[i] = run; run += c; tt += wsum[i]; }
        s_nc = run; s_ps = tt;
    }
    __syncthreads();
    const int nc = s_nc;
    int idx = wcnt[wid] + (inc - cnt);
    #pragma unroll
    for (int j = 0; j < 4; ++j)
        if (mk[j]) { bposw[b * L_ + idx] = tid * 4 + j; ++idx; }
    if (tid == 0) {
        ncw[b] = nc;
        float G  = s_ps * (1.f / L_);
        float Fm = (float)nc * (1.f / L_);
        // 0.03/8 * 1.2 * (5 Fm G + (1-Fm)(1-G))
        atomicAdd(aux_out, 0.0045f * (5.f * Fm * G + (1.f - Fm) * (1.f - G)));
    }
    __syncthreads();
    #pragma unroll
    for (int j = 0; j < 4; ++j) {
        int i = tid * 4 + j;
        float len = 0.f;
        if (i < nc) {
            int pi  = bposw[b * L_ + i];
            int nxt = (i + 1 < nc) ? bposw[b * L_ + i + 1] : L_;
            len = (float)(nxt - pi);
        }
        out_lens[b * L_ + i] = len;
    }
}

__global__ __launch_bounds__(256)
void gather_ds(const float* __restrict__ tokens, const float* __restrict__ probsw,
               const int* __restrict__ bposw, const int* __restrict__ ncw,
               float* __restrict__ out)
{
    const int row = blockIdx.x;
    const int b = row >> 12, i = row & 4095;
    const int nc = ncw[b];
    float4 v = make_float4(0.f, 0.f, 0.f, 0.f);
    if (i < nc) {
        const int t = bposw[b * L_ + i];
        const float pv = probsw[b * L_ + t];
        float4 tv = *(const float4*)&tokens[((size_t)(b << 12) + t) * D_ + threadIdx.x * 4];
        v = make_float4(tv.x * pv, tv.y * pv, tv.z * pv, tv.w * pv);
    }
    *(float4*)&out[(size_t)row * D_ + threadIdx.x * 4] = v;
}

// ===========================================================================
// Fallback kernels (fp32 vector GEMM) — used only if ws_size is too small
// ===========================================================================
__global__ __launch_bounds__(256, 2)
void gemm_cos(const float* __restrict__ A, const float* __restrict__ W,
              float* __restrict__ dotw, float* __restrict__ qn2w,
              float* __restrict__ ksn2w,
              float* __restrict__ qrow, float* __restrict__ krow)
{
    __shared__ float smem[17408];
    float* As = smem;
    float* Bs = smem + 32 * 132;

    const int tile_n = blockIdx.x;
    const int tile_m = blockIdx.y;
    const int m0 = tile_m * BM;
    const int n0 = tile_n * 64;
    const int tid = threadIdx.x;
    const int tx = tid & 15;
    const int ty = tid >> 4;

    float acc_q[8][4] = {};
    float acc_k[8][4] = {};

    for (int kt = 0; kt < D_; kt += 32) {
        #pragma unroll
        for (int i = 0; i < 4; ++i) {
            int seg = tid + 256 * i;
            int m = seg >> 3, k8 = seg & 7;
            float4 v = *reinterpret_cast<const float4*>(
                A + (size_t)(m0 + m) * D_ + kt + k8 * 4);
            As[(k8 * 4 + 0) * 132 + m] = v.x;
            As[(k8 * 4 + 1) * 132 + m] = v.y;
            As[(k8 * 4 + 2) * 132 + m] = v.z;
            As[(k8 * 4 + 3) * 132 + m] = v.w;
        }
        #pragma unroll
        for (int i = 0; i < 4; ++i) {
            int seg = tid + 256 * i;
            int k = seg >> 5, rest = seg & 31, half = rest >> 4, f4 = rest & 15;
            float4 v = *reinterpret_cast<const float4*>(
                W + (size_t)(kt + k) * 2048 + half * 1024 + n0 + f4 * 4);
            *reinterpret_cast<float4*>(&Bs[k * 132 + half * 64 + f4 * 4]) = v;
        }
        __syncthreads();
        #pragma unroll 8
        for (int k = 0; k < 32; ++k) {
            float a0[4], a1[4], bq[4], bk[4];
            *(float4*)a0 = *(float4*)&As[k * 132 + ty * 8];
            *(float4*)a1 = *(float4*)&As[k * 132 + ty * 8 + 4];
            *(float4*)bq = *(float4*)&Bs[k * 132 + tx * 4];
            *(float4*)bk = *(float4*)&Bs[k * 132 + 64 + tx * 4];
            #pragma unroll
            for (int i = 0; i < 4; ++i)
                #pragma unroll
                for (int j = 0; j < 4; ++j) {
                    acc_q[i][j]     += a0[i] * bq[j];
                    acc_q[4 + i][j] += a1[i] * bq[j];
                    acc_k[i][j]     += a0[i] * bk[j];
                    acc_k[4 + i][j] += a1[i] * bk[j];
                }
        }
        __syncthreads();
    }

    float* Q  = smem;
    float* Kl = smem + 128 * 68;
    #pragma unroll
    for (int i = 0; i < 8; ++i) {
        *(float4*)&Q [(ty * 8 + i) * 68 + tx * 4] =
            make_float4(acc_q[i][0], acc_q[i][1], acc_q[i][2], acc_q[i][3]);
        *(float4*)&Kl[(ty * 8 + i) * 68 + tx * 4] =
            make_float4(acc_k[i][0], acc_k[i][1], acc_k[i][2], acc_k[i][3]);
    }
    __syncthreads();

    const int r = tid >> 1, h = tid & 1;
    float q2 = 0.f, d = 0.f, k2 = 0.f;
    #pragma unroll
    for (int c = 0; c < 32; c += 4) {
        float4 qv = *(float4*)&Q[r * 68 + h * 32 + c];
        q2 += qv.x * qv.x + qv.y * qv.y + qv.z * qv.z + qv.w * qv.w;
    }
    if (r >= 1) {
        #pragma unroll
        for (int c = 0; c < 32; c += 4) {
            float4 qv = *(float4*)&Q [r * 68 + h * 32 + c];
            float4 kv = *(float4*)&Kl[(r - 1) * 68 + h * 32 + c];
            d  += qv.x * kv.x + qv.y * kv.y + qv.z * kv.z + qv.w * kv.w;
            k2 += kv.x * kv.x + kv.y * kv.y + kv.z * kv.z + kv.w * kv.w;
        }
    }
    q2 += __shfl_down(q2, 1, 64);
    d  += __shfl_down(d,  1, 64);
    k2 += __shfl_down(k2, 1, 64);
    if (h == 0) {
        const int m = m0 + r;
        atomicAdd(&qn2w[m], q2);
        if (r >= 1) { atomicAdd(&dotw[m], d); atomicAdd(&ksn2w[m], k2); }
    }
    if (tid < 16)
        *(float4*)&qrow[(size_t)tile_m * D_ + n0 + tid * 4] = *(float4*)&Q[0 * 68 + tid * 4];
    else if (tid < 32) {
        int t2 = tid - 16;
        *(float4*)&krow[(size_t)tile_m * D_ + n0 + t2 * 4] = *(float4*)&Kl[127 * 68 + t2 * 4];
    }
}

__global__ __launch_bounds__(256)
void boundary_fix(const float* __restrict__ qrow, const float* __restrict__ krow,
                  const float* __restrict__ start_key,
                  float* __restrict__ dotw, float* __restrict__ ksn2w)
{
    const int tile = blockIdx.x;
    const int m = tile * BM;
    const int tid = threadIdx.x;
    const float* q  = qrow + (size_t)tile * D_;
    const float* ks = ((tile & 31) == 0) ? start_key : (krow + (size_t)(tile - 1) * D_);

    float4 qv = *(const float4*)&q[tid * 4];
    float4 kv = *(const float4*)&ks[tid * 4];
    float d  = qv.x * kv.x + qv.y * kv.y + qv.z * kv.z + qv.w * kv.w;
    float k2 = kv.x * kv.x + kv.y * kv.y + kv.z * kv.z + kv.w * kv.w;

    #pragma unroll
    for (int off = 32; off; off >>= 1) {
        d  += __shfl_down(d, off, 64);
        k2 += __shfl_down(k2, off, 64);
    }
    __shared__ float sd[4], sk[4];
    const int lane = tid & 63, wid = tid >> 6;
    if (lane == 0) { sd[wid] = d; sk[wid] = k2; }
    __syncthreads();
    if (tid == 0) {
        dotw[m]  = sd[0] + sd[1] + sd[2] + sd[3];
        ksn2w[m] = sk[0] + sk[1] + sk[2] + sk[3];
    }
}

__global__ __launch_bounds__(1024)
void chunk_scan(const float* __restrict__ dotw, const float* __restrict__ qn2w,
                const float* __restrict__ ksn2w, float* __restrict__ probsw,
                int* __restrict__ bposw, int* __restrict__ ncw,
                float* __restrict__ auxw, float* __restrict__ out_lens)
{
    const int b = blockIdx.x, tid = threadIdx.x;
    const int lane = tid & 63, wid = tid >> 6;
    __shared__ int wcnt[16];
    __shared__ float wsum[16];
    __shared__ int s_nc;
    __shared__ float s_ps;

    const int base = b * L_ + tid * 4;
    float4 dv = *(const float4*)&dotw[base];
    float4 qv = *(const float4*)&qn2w[base];
    float4 kv = *(const float4*)&ksn2w[base];
    const float ds4[4] = {dv.x, dv.y, dv.z, dv.w};
    const float qs4[4] = {qv.x, qv.y, qv.z, qv.w};
    const float ks4[4] = {kv.x, kv.y, kv.z, kv.w};

    float p[4]; bool mk[4]; int cnt = 0; float psum = 0.f;
    #pragma unroll
    for (int j = 0; j < 4; ++j) {
        float qn = fmaxf(sqrtf(qs4[j]), 1e-8f);
        float kn = fmaxf(sqrtf(ks4[j]), 1e-8f);
        p[j] = 0.5f * (1.f - ds4[j] / (qn * kn));
        mk[j] = (p[j] > 0.5f) || ((tid * 4 + j) == 0);
        cnt += mk[j] ? 1 : 0;
        psum += p[j];
    }
    *(float4*)&probsw[base] = make_float4(p[0], p[1], p[2], p[3]);

    int inc = cnt;
    #pragma unroll
    for (int off = 1; off < 64; off <<= 1) {
        int nn = __shfl_up(inc, off, 64);
        if (lane >= off) inc += nn;
    }
    float ps = psum;
    #pragma unroll
    for (int off = 32; off; off >>= 1) ps += __shfl_down(ps, off, 64);
    if (lane == 63) wcnt[wid] = inc;
    if (lane == 0)  wsum[wid] = ps;
    __syncthreads();
    if (tid == 0) {
        int run = 0; float t = 0.f;
        for (int i = 0; i < 16; ++i) { int c = wcnt[i]; wcnt[i] = run; run += c; t += wsum[i]; }
        s_nc = run; s_ps = t;
    }
    __syncthreads();
    const int nc = s_nc;
    int idx = wcnt[wid] + (inc - cnt);
    #pragma unroll
    for (int j = 0; j < 4; ++j)
        if (mk[j]) { bposw[b * L_ + idx] = tid * 4 + j; ++idx; }
    if (tid == 0) {
        ncw[b] = nc;
        float G  = s_ps * (1.f / L_);
        float Fm = (float)nc * (1.f / L_);
        auxw[b] = 1.2f * (5.f * Fm * G + (1.f - Fm) * (1.f - G));
    }
    __syncthreads();
    #pragma unroll
    for (int j = 0; j < 4; ++j) {
        int i = tid * 4 + j;
        float len = 0.f;
        if (i < nc) {
            int pi  = bposw[b * L_ + i];
            int nxt = (i + 1 < nc) ? bposw[b * L_ + i + 1] : L_;
            len = (float)(nxt - pi);
        }
        out_lens[b * L_ + i] = len;
    }
}

__global__ void aux_final(const float* __restrict__ auxw, float* __restrict__ out_scalar)
{
    if (threadIdx.x == 0) {
        float s = 0.f;
        for (int i = 0; i < B_; ++i) s += auxw[i];
        *out_scalar = 0.03f * (s * (1.f / B_));
    }
}

// ===========================================================================
extern "C" void kernel_launch(void* const* d_in, const int* in_sizes, int n_in,
                              void* d_out, int out_size, void* d_ws, size_t ws_size,
                              hipStream_t stream)
{
    const float* tokens    = (const float*)d_in[0];
    const float* W_qk      = (const float*)d_in[1];
    const float* start_key = (const float*)d_in[2];
    float* out = (float*)d_out;
    float* lens_out = out + DS_ELEMS;
    float* aux_out  = out + DS_ELEMS + M_TOT;

    const size_t need_fast = (size_t)2789396 * 4;   // ~11.2 MB

    if (ws_size >= need_fast) {
        float* wf = (float*)d_ws;
        float* dotw   = wf;                  // 32768
        float* qn2w   = wf + 32768;          // 32768
        float* ksn2w  = wf + 65536;          // 32768
        int*   scount = (int*)(wf + 98304);  // 1
        float* probsw = wf + 98308;          // 32768
        int*   bposw  = (int*)(wf + 131076); // 32768
        int*   ncw    = (int*)(wf + 163844); // 8
        int*   slist  = (int*)(wf + 163860); // 4096
        float* qrow   = wf + 167956;         // 262144
        float* krow   = wf + 430100;         // 262144
        __bf16* wT_hi = (__bf16*)(wf + 692244);   // 2097152 bf16
        __bf16* wT_lo = (__bf16*)(wf + 1740820);  // 2097152 bf16
        __bf16* t_hi = (__bf16*)out;              // in d_out, overwritten by gather
        __bf16* t_lo = (__bf16*)(out + 16777216);

        hipMemsetAsync(d_ws, 0, 393220, stream);   // dot/qn2/ksn2 + scount
        hipMemsetAsync(aux_out, 0, 4, stream);

        split_tokens<<<32768, 256, 0, stream>>>(tokens, t_hi, t_lo);
        split_wT<<<dim3(32, 64), 256, 0, stream>>>(W_qk, wT_hi, wT_lo);

        gemm_cos_mfma<<<dim3(16, 256), 256, 0, stream>>>(
            t_hi, t_lo, wT_hi, wT_lo, dotw, qn2w, ksn2w, qrow, krow);

        probs_fused<<<256, 256, 0, stream>>>(qrow, krow, start_key, dotw, qn2w,
                                             ksn2w, probsw, scount, slist);
        fixup<<<128, 256, 0, stream>>>(tokens, W_qk, start_key, scount, slist, probsw);
        chunk_scan_p<<<B_, 1024, 0, stream>>>(probsw, bposw, ncw, aux_out, lens_out);
        gather_ds<<<M_TOT, 256, 0, stream>>>(tokens, probsw, bposw, ncw, out);
    } else {
        float* wf = (float*)d_ws;
        float* dotw   = wf;
        float* qn2w   = wf + 32768;
        float* ksn2w  = wf + 65536;
        float* probsw = wf + 98304;
        int*   bposw  = (int*)(wf + 131072);
        int*   ncw    = (int*)(wf + 163840);
        float* auxw   = wf + 163856;
        float* qrow   = wf + 163872;
        float* krow   = wf + 426016;

        hipMemsetAsync(d_ws, 0, (size_t)3 * M_TOT * sizeof(float), stream);
        gemm_cos<<<dim3(16, 256), 256, 0, stream>>>(
            tokens, W_qk, dotw, qn2w, ksn2w, qrow, krow);
        boundary_fix<<<256, 256, 0, stream>>>(qrow, krow, start_key, dotw, ksn2w);
        chunk_scan<<<B_, 1024, 0, stream>>>(dotw, qn2w, ksn2w, probsw, bposw, ncw,
                                            auxw, lens_out);
        aux_final<<<1, 64, 0, stream>>>(auxw, aux_out);
        gather_ds<<<M_TOT, 256, 0, stream>>>(tokens, probsw, bposw, ncw, out);
    }
}

// Round 4
// 726.588 us; speedup vs baseline: 2.2975x; 1.2895x over previous
//
#include <hip/hip_runtime.h>
#include <hip/hip_bf16.h>
#include <hip/hip_fp16.h>

// DynamicSequenceChunker: B=8, L=4096, D=1024, DK=1024
// R4: fp16 single-slab main MFMA GEMM (3x less work than bf16 3-slab) +
//     precision cascade: |cos|<1e-3 suspects -> batched bf16 3-slab GEMM ->
//     |cos|<1e-4 sub-suspects -> fp32 per-row fixup.
//     XCD-swizzled grid; all splits+zeroing fused into one prep kernel.

#define B_ 8
#define L_ 4096
#define D_ 1024
#define M_TOT (B_ * L_)                 // 32768
#define BM 128
#define DS_ELEMS ((size_t)M_TOT * D_)   // 33554432
#define SUS_CAP 2048

typedef _Float16 f16x8 __attribute__((ext_vector_type(8)));
typedef _Float16 f16x4 __attribute__((ext_vector_type(4)));
typedef __bf16  bf16x8 __attribute__((ext_vector_type(8)));
typedef __bf16  bf16x4 __attribute__((ext_vector_type(4)));
typedef float   f32x4  __attribute__((ext_vector_type(4)));

typedef __attribute__((address_space(1))) void gv_t;
typedef __attribute__((address_space(3))) void lv_t;

__device__ __forceinline__ void gl_lds16(const void* g, void* l) {
    __builtin_amdgcn_global_load_lds((gv_t*)g, (lv_t*)l, 16, 0, 0);
}

// ---------------------------------------------------------------------------
// prep: tokens->fp16, W->wT fp16 + wT bf16 hi/lo, zero accumulators+counters
// grid: 8192 (tokens) + 2048 (wT tiles) + 97 (zero) = 10337 blocks
// ---------------------------------------------------------------------------
__global__ __launch_bounds__(256)
void prep(const float* __restrict__ tokens, const float* __restrict__ W,
          _Float16* __restrict__ t_h, _Float16* __restrict__ wT_h,
          __bf16* __restrict__ wT_hi, __bf16* __restrict__ wT_lo,
          float* __restrict__ zbase, float* __restrict__ aux_out)
{
    const int bid = blockIdx.x, tid = threadIdx.x;
    if (bid < 8192) {
        const size_t base = (size_t)bid * 4096 + tid * 4;
        #pragma unroll
        for (int r = 0; r < 4; ++r) {
            size_t idx = base + (size_t)r * 1024;
            float4 v = *(const float4*)&tokens[idx];
            f16x4 h;
            h[0] = (_Float16)v.x; h[1] = (_Float16)v.y;
            h[2] = (_Float16)v.z; h[3] = (_Float16)v.w;
            *(f16x4*)&t_h[idx] = h;
        }
    } else if (bid < 10240) {
        __shared__ float lw[32 * 33];
        const int local = bid - 8192;
        const int k0 = (local & 31) * 32;
        const int n0 = (local >> 5) * 32;
        {
            const int lk = tid >> 3, ln4 = (tid & 7) * 4;
            float4 v = *(const float4*)&W[(size_t)(k0 + lk) * 2048 + n0 + ln4];
            lw[(ln4 + 0) * 33 + lk] = v.x;
            lw[(ln4 + 1) * 33 + lk] = v.y;
            lw[(ln4 + 2) * 33 + lk] = v.z;
            lw[(ln4 + 3) * 33 + lk] = v.w;
        }
        __syncthreads();
        {
            const int ln = tid >> 3, lk4 = (tid & 7) * 4;
            f16x4 h; bf16x4 bh, bl;
            #pragma unroll
            for (int j = 0; j < 4; ++j) {
                float v = lw[ln * 33 + lk4 + j];
                h[j] = (_Float16)v;
                __bf16 b = (__bf16)v;
                bh[j] = b;
                bl[j] = (__bf16)(v - (float)b);
            }
            size_t o = (size_t)(n0 + ln) * 1024 + k0 + lk4;
            *(f16x4*)&wT_h[o]   = h;
            *(bf16x4*)&wT_hi[o] = bh;
            *(bf16x4*)&wT_lo[o] = bl;
        }
    } else {
        const int zb = bid - 10240;                // 0..96
        const int i = zb * 1024 + tid * 4;
        if (i < 98308)
            *(float4*)&zbase[i] = make_float4(0.f, 0.f, 0.f, 0.f);
        if (zb == 0 && tid == 0) *aux_out = 0.f;
    }
}

// ---------------------------------------------------------------------------
// main GEMM: fp16 single-slab, tile 128 rows x (64 q-cols + 64 k-cols)
// grid 4096 linear, XCD-swizzled: blocks sharing tile_m land on one XCD
// ---------------------------------------------------------------------------
__global__ __launch_bounds__(256, 2)
void gemm_cos_f16(const _Float16* __restrict__ t_h, const _Float16* __restrict__ wT_h,
                  float* __restrict__ dotw, float* __restrict__ qn2w,
                  float* __restrict__ ksn2w,
                  float* __restrict__ qrow, float* __restrict__ krow)
{
    __shared__ float smem[8448];                    // 33792 B
    _Float16* As = (_Float16*)smem;                 // [128 m][32 k] swizzled
    _Float16* Bs = (_Float16*)smem + 4096;          // [128 n][32 k] swizzled
    float*    Ck = smem;                            // epilogue [128][66]

    const int bx = blockIdx.x;
    const int tile_n = (bx >> 3) & 15;
    const int tile_m = ((bx >> 7) & 31) + ((bx & 7) << 5);
    const int m0 = tile_m * BM;
    const int n0 = tile_n * 64;
    const int tid  = threadIdx.x;
    const int w    = tid >> 6;
    const int lane = tid & 63;
    const int quad = lane >> 4;
    const int lc   = lane & 15;

    const int wm  = (w & 1) * 64;
    const int wq0 = (w >> 1) * 32;

    const int ia0 = w * 2, ia1 = w * 2 + 1;
    const int st_ch = ((lane & 3) ^ ((lane >> 3) & 3)) * 8;
    const size_t a_g0 = (size_t)(m0 + ia0 * 16 + (lane >> 2)) * 1024 + st_ch;
    const size_t a_g1 = a_g0 + (size_t)16 * 1024;
    const int br0 = ia0 * 16 + (lane >> 2);
    const int br1 = br0 + 16;
    const int gr0 = (br0 < 64) ? (n0 + br0) : (960 + n0 + br0);
    const int gr1 = (br1 < 64) ? (n0 + br1) : (960 + n0 + br1);
    const size_t b_g0 = (size_t)gr0 * 1024 + st_ch;
    const size_t b_g1 = (size_t)gr1 * 1024 + st_ch;
    char* aL0 = (char*)smem + ia0 * 1024;
    char* aL1 = (char*)smem + ia1 * 1024;
    char* bL0 = (char*)smem + 8192 + ia0 * 1024;
    char* bL1 = (char*)smem + 8192 + ia1 * 1024;

    const int fr_ch = (quad ^ ((lc >> 1) & 3)) * 8;

    f32x4 accq[4][2] = {};
    f32x4 acck[4][2] = {};

    for (int kk = 0; kk < 32; ++kk) {
        const size_t kb = (size_t)kk * 32;
        gl_lds16(t_h  + a_g0 + kb, aL0);
        gl_lds16(t_h  + a_g1 + kb, aL1);
        gl_lds16(wT_h + b_g0 + kb, bL0);
        gl_lds16(wT_h + b_g1 + kb, bL1);
        __syncthreads();

        f16x8 af[4], bq[2], bk[2];
        #pragma unroll
        for (int mi = 0; mi < 4; ++mi)
            af[mi] = *(const f16x8*)(As + (wm + mi * 16 + lc) * 32 + fr_ch);
        #pragma unroll
        for (int ni = 0; ni < 2; ++ni) {
            bq[ni] = *(const f16x8*)(Bs + (wq0 + ni * 16 + lc) * 32 + fr_ch);
            bk[ni] = *(const f16x8*)(Bs + (64 + wq0 + ni * 16 + lc) * 32 + fr_ch);
        }
        #pragma unroll
        for (int mi = 0; mi < 4; ++mi) {
            #pragma unroll
            for (int ni = 0; ni < 2; ++ni) {
                accq[mi][ni] = __builtin_amdgcn_mfma_f32_16x16x32_f16(
                    af[mi], bq[ni], accq[mi][ni], 0, 0, 0);
                acck[mi][ni] = __builtin_amdgcn_mfma_f32_16x16x32_f16(
                    af[mi], bk[ni], acck[mi][ni], 0, 0, 0);
            }
        }
        __syncthreads();
    }

    // ---- epilogue (same as validated bf16 version) ----
    #pragma unroll
    for (int mi = 0; mi < 4; ++mi) {
        #pragma unroll
        for (int reg = 0; reg < 4; ++reg) {
            const int row = wm + mi * 16 + quad * 4 + reg;
            float s = accq[mi][0][reg] * accq[mi][0][reg]
                    + accq[mi][1][reg] * accq[mi][1][reg];
            s += __shfl_xor(s, 1); s += __shfl_xor(s, 2);
            s += __shfl_xor(s, 4); s += __shfl_xor(s, 8);
            if (lc == 0) atomicAdd(&qn2w[m0 + row], s);

            float s2 = acck[mi][0][reg] * acck[mi][0][reg]
                     + acck[mi][1][reg] * acck[mi][1][reg];
            s2 += __shfl_xor(s2, 1); s2 += __shfl_xor(s2, 2);
            s2 += __shfl_xor(s2, 4); s2 += __shfl_xor(s2, 8);
            if (lc == 0 && row < 127) atomicAdd(&ksn2w[m0 + row + 1], s2);
        }
    }

    #pragma unroll
    for (int mi = 0; mi < 4; ++mi)
        #pragma unroll
        for (int ni = 0; ni < 2; ++ni)
            #pragma unroll
            for (int reg = 0; reg < 4; ++reg)
                Ck[(wm + mi * 16 + quad * 4 + reg) * 66 + wq0 + ni * 16 + lc] =
                    acck[mi][ni][reg];
    __syncthreads();

    #pragma unroll
    for (int mi = 0; mi < 4; ++mi) {
        #pragma unroll
        for (int reg = 0; reg < 4; ++reg) {
            const int row = wm + mi * 16 + quad * 4 + reg;
            float d = 0.f;
            if (row >= 1)
                d = accq[mi][0][reg] * Ck[(row - 1) * 66 + wq0 + lc]
                  + accq[mi][1][reg] * Ck[(row - 1) * 66 + wq0 + 16 + lc];
            d += __shfl_xor(d, 1); d += __shfl_xor(d, 2);
            d += __shfl_xor(d, 4); d += __shfl_xor(d, 8);
            if (lc == 0 && row >= 1) atomicAdd(&dotw[m0 + row], d);
        }
    }

    if (wm == 0 && quad == 0) {
        #pragma unroll
        for (int ni = 0; ni < 2; ++ni)
            qrow[(size_t)tile_m * D_ + n0 + wq0 + ni * 16 + lc] = accq[0][ni][0];
    }
    if (wm == 64 && quad == 3) {
        #pragma unroll
        for (int ni = 0; ni < 2; ++ni)
            krow[(size_t)tile_m * D_ + n0 + wq0 + ni * 16 + lc] = acck[3][ni][3];
    }
}

// ---------------------------------------------------------------------------
// fused: boundary dot (t ≡ 0 mod 128) + probs + suspect list (|cos| < 1e-3)
// ---------------------------------------------------------------------------
__global__ __launch_bounds__(256)
void probs_fused(const float* __restrict__ qrow, const float* __restrict__ krow,
                 const float* __restrict__ start_key,
                 const float* __restrict__ dotw, const float* __restrict__ qn2w,
                 const float* __restrict__ ksn2w, float* __restrict__ probsw,
                 int* __restrict__ scount, int* __restrict__ slist)
{
    const int tile = blockIdx.x;
    const int tid = threadIdx.x;
    __shared__ float sd[4], sk[4];

    {
        const float* q  = qrow + (size_t)tile * D_;
        const float* ks = ((tile & 31) == 0) ? start_key
                                             : (krow + (size_t)(tile - 1) * D_);
        float4 qv = *(const float4*)&q[tid * 4];
        float4 kv = *(const float4*)&ks[tid * 4];
        float d  = qv.x * kv.x + qv.y * kv.y + qv.z * kv.z + qv.w * kv.w;
        float k2 = kv.x * kv.x + kv.y * kv.y + kv.z * kv.z + kv.w * kv.w;
        #pragma unroll
        for (int off = 32; off; off >>= 1) {
            d  += __shfl_down(d, off, 64);
            k2 += __shfl_down(k2, off, 64);
        }
        const int lane = tid & 63, wid = tid >> 6;
        if (lane == 0) { sd[wid] = d; sk[wid] = k2; }
    }
    __syncthreads();

    if (tid < BM) {
        const int m = tile * BM + tid;
        float dd = dotw[m], kk = ksn2w[m];
        if (tid == 0) {
            dd = sd[0] + sd[1] + sd[2] + sd[3];
            kk = sk[0] + sk[1] + sk[2] + sk[3];
        }
        float qn = fmaxf(sqrtf(qn2w[m]), 1e-8f);
        float kn = fmaxf(sqrtf(kk), 1e-8f);
        float c = dd / (qn * kn);
        probsw[m] = 0.5f * (1.f - c);
        if (fabsf(c) < 1e-3f) {
            int i = atomicAdd(scount, 1);
            if (i < SUS_CAP) slist[i] = m;
        }
    }
}

// ---------------------------------------------------------------------------
// stage-2 operand build: gather suspect rows (and predecessors) -> bf16 hi/lo
// slots [0,2048): token[t_s]; slots [2048,4096): token[t_s - 1] (or dummy)
// ---------------------------------------------------------------------------
__global__ __launch_bounds__(256)
void gather_split(const float* __restrict__ tokens, const int* __restrict__ scount,
                  const int* __restrict__ slist,
                  __bf16* __restrict__ As_hi, __bf16* __restrict__ As_lo)
{
    int n = *scount; if (n > SUS_CAP) n = SUS_CAP;
    const int n_up = (n + 127) & ~127;
    const int slot = blockIdx.x;
    const int sl = slot & 2047;
    if (sl >= n_up) return;
    const int tid = threadIdx.x;

    int src = -1;
    if (sl < n) {
        int t = slist[sl];
        if (slot < 2048) src = t;
        else src = ((t & 4095) == 0) ? t : (t - 1);
    }
    bf16x4 h = {}, l = {};
    if (src >= 0) {
        float4 v = *(const float4*)&tokens[(size_t)src * 1024 + tid * 4];
        float vs[4] = {v.x, v.y, v.z, v.w};
        #pragma unroll
        for (int j = 0; j < 4; ++j) {
            __bf16 b = (__bf16)vs[j];
            h[j] = b;
            l[j] = (__bf16)(vs[j] - (float)b);
        }
    }
    size_t o = (size_t)slot * 1024 + tid * 4;
    *(bf16x4*)&As_hi[o] = h;
    *(bf16x4*)&As_lo[o] = l;
}

// ---------------------------------------------------------------------------
// stage-2 GEMM: bf16 3-slab on gathered rows, writes C2 [4096 x 2048] fp32
// grid (16 n-tiles, 32 m-tiles); inactive m-tiles exit
// ---------------------------------------------------------------------------
__global__ __launch_bounds__(256, 2)
void gemm2(const __bf16* __restrict__ As_hi, const __bf16* __restrict__ As_lo,
           const __bf16* __restrict__ wT_hi, const __bf16* __restrict__ wT_lo,
           const int* __restrict__ scount, float* __restrict__ C2)
{
    int n = *scount; if (n > SUS_CAP) n = SUS_CAP;
    const int tm = blockIdx.y;
    const int local_base = (tm < 16) ? tm * 128 : (tm - 16) * 128;
    if (local_base >= n) return;
    const int m0 = (tm < 16) ? tm * 128 : 2048 + (tm - 16) * 128;

    __shared__ float smem[4096];                    // 16 KB staging
    __bf16* As = (__bf16*)smem;
    __bf16* Bs = (__bf16*)smem + 4096;

    const int tile_n = blockIdx.x;
    const int n0 = tile_n * 64;
    const int tid  = threadIdx.x;
    const int w    = tid >> 6;
    const int lane = tid & 63;
    const int quad = lane >> 4;
    const int lc   = lane & 15;
    const int wm  = (w & 1) * 64;
    const int wq0 = (w >> 1) * 32;

    const int ia0 = w * 2, ia1 = w * 2 + 1;
    const int st_ch = ((lane & 3) ^ ((lane >> 3) & 3)) * 8;
    const size_t a_g0 = (size_t)(m0 + ia0 * 16 + (lane >> 2)) * 1024 + st_ch;
    const size_t a_g1 = a_g0 + (size_t)16 * 1024;
    const int br0 = ia0 * 16 + (lane >> 2);
    const int br1 = br0 + 16;
    const int gr0 = (br0 < 64) ? (n0 + br0) : (960 + n0 + br0);
    const int gr1 = (br1 < 64) ? (n0 + br1) : (960 + n0 + br1);
    const size_t b_g0 = (size_t)gr0 * 1024 + st_ch;
    const size_t b_g1 = (size_t)gr1 * 1024 + st_ch;
    char* aL0 = (char*)smem + ia0 * 1024;
    char* aL1 = (char*)smem + ia1 * 1024;
    char* bL0 = (char*)smem + 8192 + ia0 * 1024;
    char* bL1 = (char*)smem + 8192 + ia1 * 1024;
    const int fr_ch = (quad ^ ((lc >> 1) & 3)) * 8;

    f32x4 accq[4][2] = {};
    f32x4 acck[4][2] = {};

    for (int kk = 0; kk < 96; ++kk) {
        const int slab = kk >> 5;
        const size_t kb = (size_t)(kk & 31) * 32;
        const __bf16* Ap = (slab < 2) ? As_hi : As_lo;
        const __bf16* Bp = (slab == 1) ? wT_lo : wT_hi;

        gl_lds16(Ap + a_g0 + kb, aL0);
        gl_lds16(Ap + a_g1 + kb, aL1);
        gl_lds16(Bp + b_g0 + kb, bL0);
        gl_lds16(Bp + b_g1 + kb, bL1);
        __syncthreads();

        bf16x8 af[4], bq[2], bk[2];
        #pragma unroll
        for (int mi = 0; mi < 4; ++mi)
            af[mi] = *(const bf16x8*)(As + (wm + mi * 16 + lc) * 32 + fr_ch);
        #pragma unroll
        for (int ni = 0; ni < 2; ++ni) {
            bq[ni] = *(const bf16x8*)(Bs + (wq0 + ni * 16 + lc) * 32 + fr_ch);
            bk[ni] = *(const bf16x8*)(Bs + (64 + wq0 + ni * 16 + lc) * 32 + fr_ch);
        }
        #pragma unroll
        for (int mi = 0; mi < 4; ++mi) {
            #pragma unroll
            for (int ni = 0; ni < 2; ++ni) {
                accq[mi][ni] = __builtin_amdgcn_mfma_f32_16x16x32_bf16(
                    af[mi], bq[ni], accq[mi][ni], 0, 0, 0);
                acck[mi][ni] = __builtin_amdgcn_mfma_f32_16x16x32_bf16(
                    af[mi], bk[ni], acck[mi][ni], 0, 0, 0);
            }
        }
        __syncthreads();
    }

    #pragma unroll
    for (int mi = 0; mi < 4; ++mi) {
        #pragma unroll
        for (int reg = 0; reg < 4; ++reg) {
            const int row = m0 + wm + mi * 16 + quad * 4 + reg;
            #pragma unroll
            for (int ni = 0; ni < 2; ++ni) {
                C2[(size_t)row * 2048 + n0 + wq0 + ni * 16 + lc] = accq[mi][ni][reg];
                C2[(size_t)row * 2048 + 1024 + n0 + wq0 + ni * 16 + lc] = acck[mi][ni][reg];
            }
        }
    }
}

// ---------------------------------------------------------------------------
// stage-2 resolve: dot/norms from C2; sub-suspects (|cos|<1e-4) -> slist2
// ---------------------------------------------------------------------------
__global__ __launch_bounds__(256)
void dot_fix(const float* __restrict__ C2, const float* __restrict__ start_key,
             const int* __restrict__ scount, const int* __restrict__ slist,
             float* __restrict__ probsw, int* __restrict__ scount2,
             int* __restrict__ slist2)
{
    int n = *scount; if (n > SUS_CAP) n = SUS_CAP;
    const int s = blockIdx.x;
    if (s >= n) return;
    const int tid = threadIdx.x;
    const int t = slist[s];
    const bool st = (t & 4095) == 0;
    const float* q = C2 + (size_t)s * 2048;
    const float* k = st ? start_key : (C2 + (size_t)(2048 + s) * 2048 + 1024);

    float4 qv = *(const float4*)&q[tid * 4];
    float4 kv = *(const float4*)&k[tid * 4];
    float d  = qv.x * kv.x + qv.y * kv.y + qv.z * kv.z + qv.w * kv.w;
    float q2 = qv.x * qv.x + qv.y * qv.y + qv.z * qv.z + qv.w * qv.w;
    float k2 = kv.x * kv.x + kv.y * kv.y + kv.z * kv.z + kv.w * kv.w;
    #pragma unroll
    for (int off = 32; off; off >>= 1) {
        d  += __shfl_down(d, off, 64);
        q2 += __shfl_down(q2, off, 64);
        k2 += __shfl_down(k2, off, 64);
    }
    __shared__ float sd[4], sq[4], sk[4];
    const int lane = tid & 63, wid = tid >> 6;
    if (lane == 0) { sd[wid] = d; sq[wid] = q2; sk[wid] = k2; }
    __syncthreads();
    if (tid == 0) {
        float D  = sd[0] + sd[1] + sd[2] + sd[3];
        float Q2 = sq[0] + sq[1] + sq[2] + sq[3];
        float K2 = sk[0] + sk[1] + sk[2] + sk[3];
        float c = D / (fmaxf(sqrtf(Q2), 1e-8f) * fmaxf(sqrtf(K2), 1e-8f));
        if (fabsf(c) < 1e-4f) {
            int i = atomicAdd(scount2, 1);
            if (i < SUS_CAP) slist2[i] = t;
        } else {
            probsw[t] = 0.5f * (1.f - c);
        }
    }
}

// ---------------------------------------------------------------------------
// stage-3: exact fp32 per-row recompute of sub-suspects
// ---------------------------------------------------------------------------
__global__ __launch_bounds__(256)
void fixup3(const float* __restrict__ tokens, const float* __restrict__ W,
            const float* __restrict__ start_key, const int* __restrict__ scount2,
            const int* __restrict__ slist2, float* __restrict__ probsw)
{
    __shared__ float ta[1024], tb[1024];
    __shared__ float rq[4], rk[4], rd[4];
    const int tid = threadIdx.x;
    int n = *scount2; if (n > SUS_CAP) n = SUS_CAP;

    for (int i = blockIdx.x; i < n; i += gridDim.x) {
        const int t = slist2[i];
        const bool st = (t & 4095) == 0;
        *(float4*)&ta[tid * 4] = *(const float4*)&tokens[(size_t)t * 1024 + tid * 4];
        if (!st)
            *(float4*)&tb[tid * 4] = *(const float4*)&tokens[(size_t)(t - 1) * 1024 + tid * 4];
        __syncthreads();

        float q[4] = {0, 0, 0, 0}, kv[4] = {0, 0, 0, 0};
        if (st) {
            #pragma unroll 4
            for (int k = 0; k < 1024; ++k) {
                float a = ta[k];
                float4 wq = *(const float4*)&W[(size_t)k * 2048 + tid * 4];
                q[0] = fmaf(a, wq.x, q[0]); q[1] = fmaf(a, wq.y, q[1]);
                q[2] = fmaf(a, wq.z, q[2]); q[3] = fmaf(a, wq.w, q[3]);
            }
            float4 sv = *(const float4*)&start_key[tid * 4];
            kv[0] = sv.x; kv[1] = sv.y; kv[2] = sv.z; kv[3] = sv.w;
        } else {
            #pragma unroll 4
            for (int k = 0; k < 1024; ++k) {
                float a = ta[k], b = tb[k];
                float4 wq = *(const float4*)&W[(size_t)k * 2048 + tid * 4];
                float4 wk = *(const float4*)&W[(size_t)k * 2048 + 1024 + tid * 4];
                q[0] = fmaf(a, wq.x, q[0]); q[1] = fmaf(a, wq.y, q[1]);
                q[2] = fmaf(a, wq.z, q[2]); q[3] = fmaf(a, wq.w, q[3]);
                kv[0] = fmaf(b, wk.x, kv[0]); kv[1] = fmaf(b, wk.y, kv[1]);
                kv[2] = fmaf(b, wk.z, kv[2]); kv[3] = fmaf(b, wk.w, kv[3]);
            }
        }
        float q2 = 0, k2 = 0, dd = 0;
        #pragma unroll
        for (int j = 0; j < 4; ++j) {
            q2 += q[j] * q[j]; k2 += kv[j] * kv[j]; dd += q[j] * kv[j];
        }
        #pragma unroll
        for (int off = 32; off; off >>= 1) {
            q2 += __shfl_down(q2, off, 64);
            k2 += __shfl_down(k2, off, 64);
            dd += __shfl_down(dd, off, 64);
        }
        const int lane = tid & 63, wid = tid >> 6;
        if (lane == 0) { rq[wid] = q2; rk[wid] = k2; rd[wid] = dd; }
        __syncthreads();
        if (tid == 0) {
            float Q2 = rq[0] + rq[1] + rq[2] + rq[3];
            float K2 = rk[0] + rk[1] + rk[2] + rk[3];
            float DD = rd[0] + rd[1] + rd[2] + rd[3];
            float qn = fmaxf(sqrtf(Q2), 1e-8f), kn = fmaxf(sqrtf(K2), 1e-8f);
            probsw[t] = 0.5f * (1.f - DD / (qn * kn));
        }
        __syncthreads();
    }
}

// ---------------------------------------------------------------------------
__global__ __launch_bounds__(1024)
void chunk_scan_p(const float* __restrict__ probsw, int* __restrict__ bposw,
                  int* __restrict__ ncw, float* __restrict__ aux_out,
                  float* __restrict__ out_lens)
{
    const int b = blockIdx.x, tid = threadIdx.x;
    const int lane = tid & 63, wid = tid >> 6;
    __shared__ int wcnt[16];
    __shared__ float wsum[16];
    __shared__ int s_nc;
    __shared__ float s_ps;

    const int base = b * L_ + tid * 4;
    float4 pv = *(const float4*)&probsw[base];
    const float p[4] = {pv.x, pv.y, pv.z, pv.w};

    bool mk[4]; int cnt = 0; float psum = 0.f;
    #pragma unroll
    for (int j = 0; j < 4; ++j) {
        mk[j] = (p[j] > 0.5f) || ((tid * 4 + j) == 0);
        cnt += mk[j] ? 1 : 0;
        psum += p[j];
    }
    int inc = cnt;
    #pragma unroll
    for (int off = 1; off < 64; off <<= 1) {
        int nn = __shfl_up(inc, off, 64);
        if (lane >= off) inc += nn;
    }
    float ps = psum;
    #pragma unroll
    for (int off = 32; off; off >>= 1) ps += __shfl_down(ps, off, 64);
    if (lane == 63) wcnt[wid] = inc;
    if (lane == 0)  wsum[wid] = ps;
    __syncthreads();
    if (tid == 0) {
        int run = 0; float tt = 0.f;
        for (int i = 0; i < 16; ++i) { int c = wcnt[i]; wcnt[i] = run; run += c; tt += wsum[i]; }
        s_nc = run; s_ps = tt;
    }
    __syncthreads();
    const int nc = s_nc;
    int idx = wcnt[wid] + (inc - cnt);
    #pragma unroll
    for (int j = 0; j < 4; ++j)
        if (mk[j]) { bposw[b * L_ + idx] = tid * 4 + j; ++idx; }
    if (tid == 0) {
        ncw[b] = nc;
        float G  = s_ps * (1.f / L_);
        float Fm = (float)nc * (1.f / L_);
        atomicAdd(aux_out, 0.0045f * (5.f * Fm * G + (1.f - Fm) * (1.f - G)));
    }
    __syncthreads();
    #pragma unroll
    for (int j = 0; j < 4; ++j) {
        int i = tid * 4 + j;
        float len = 0.f;
        if (i < nc) {
            int pi  = bposw[b * L_ + i];
            int nxt = (i + 1 < nc) ? bposw[b * L_ + i + 1] : L_;
            len = (float)(nxt - pi);
        }
        out_lens[b * L_ + i] = len;
    }
}

__global__ __launch_bounds__(256)
void gather_ds(const float* __restrict__ tokens, const float* __restrict__ probsw,
               const int* __restrict__ bposw, const int* __restrict__ ncw,
               float* __restrict__ out)
{
    const int row = blockIdx.x;
    const int b = row >> 12, i = row & 4095;
    const int nc = ncw[b];
    float4 v = make_float4(0.f, 0.f, 0.f, 0.f);
    if (i < nc) {
        const int t = bposw[b * L_ + i];
        const float pv = probsw[b * L_ + t];
        float4 tv = *(const float4*)&tokens[((size_t)(b << 12) + t) * D_ + threadIdx.x * 4];
        v = make_float4(tv.x * pv, tv.y * pv, tv.z * pv, tv.w * pv);
    }
    *(float4*)&out[(size_t)row * D_ + threadIdx.x * 4] = v;
}

// ===========================================================================
extern "C" void kernel_launch(void* const* d_in, const int* in_sizes, int n_in,
                              void* d_out, int out_size, void* d_ws, size_t ws_size,
                              hipStream_t stream)
{
    const float* tokens    = (const float*)d_in[0];
    const float* W_qk      = (const float*)d_in[1];
    const float* start_key = (const float*)d_in[2];
    float* out = (float*)d_out;
    float* lens_out = out + DS_ELEMS;
    float* aux_out  = out + DS_ELEMS + M_TOT;

    // ws layout (floats) — total 1740812 floats ≈ 6.96 MB
    float* wf = (float*)d_ws;
    float* dotw    = wf;                       // 32768
    float* qn2w    = wf + 32768;               // 32768
    float* ksn2w   = wf + 65536;               // 32768
    int*   scount  = (int*)(wf + 98304);       // 1
    int*   scount2 = (int*)(wf + 98305);       // 1 (+2 pad)
    float* probsw  = wf + 98308;               // 32768
    int*   bposw   = (int*)(wf + 131076);      // 32768
    int*   ncw     = (int*)(wf + 163844);      // 8
    int*   slist   = (int*)(wf + 163852);      // 2048
    int*   slist2  = (int*)(wf + 165900);      // 2048
    float* qrow    = wf + 167948;              // 262144
    float* krow    = wf + 430092;              // 262144
    _Float16* wT_h = (_Float16*)(wf + 692236); // 2097152 halves

    // d_out scratch (overwritten by gather_ds at the end)
    _Float16* t_h  = (_Float16*)out;                   // 33554432 halves
    __bf16* As_hi  = (__bf16*)(out + 16777216);        // 4096x1024
    __bf16* As_lo  = (__bf16*)(out + 18874368);
    float*  C2     = out + 20971520;                   // 4096x2048 fp32
    __bf16* wT_hi  = (__bf16*)(out + 29360128);        // 2048x1024
    __bf16* wT_lo  = (__bf16*)(out + 30408704);

    prep<<<10337, 256, 0, stream>>>(tokens, W_qk, t_h, wT_h, wT_hi, wT_lo,
                                    wf, aux_out);
    gemm_cos_f16<<<4096, 256, 0, stream>>>(t_h, wT_h, dotw, qn2w, ksn2w,
                                           qrow, krow);
    probs_fused<<<256, 256, 0, stream>>>(qrow, krow, start_key, dotw, qn2w,
                                         ksn2w, probsw, scount, slist);
    gather_split<<<4096, 256, 0, stream>>>(tokens, scount, slist, As_hi, As_lo);
    gemm2<<<dim3(16, 32), 256, 0, stream>>>(As_hi, As_lo, wT_hi, wT_lo,
                                            scount, C2);
    dot_fix<<<2048, 256, 0, stream>>>(C2, start_key, scount, slist, probsw,
                                      scount2, slist2);
    fixup3<<<128, 256, 0, stream>>>(tokens, W_qk, start_key, scount2, slist2,
                                    probsw);
    chunk_scan_p<<<B_, 1024, 0, stream>>>(probsw, bposw, ncw, aux_out, lens_out);
    gather_ds<<<M_TOT, 256, 0, stream>>>(tokens, probsw, bposw, ncw, out);
}

// Round 6
// 723.500 us; speedup vs baseline: 2.3073x; 1.0043x over previous
//
#include <hip/hip_runtime.h>
#include <hip/hip_bf16.h>
#include <hip/hip_fp16.h>

// DynamicSequenceChunker: B=8, L=4096, D=1024, DK=1024
// R6: R4 (passing, 727us) + ONE change: double-buffered LDS K-loop in the
//     fp16 main GEMM (1 barrier/iter, loads(k+1) in flight during compute(k)).
//     smem grown to 33792B so the R4 epilogue (Ck [128][66]) stays identical.
//     launch_bounds(256,2) and all tail kernels byte-identical to R4.

#define B_ 8
#define L_ 4096
#define D_ 1024
#define M_TOT (B_ * L_)                 // 32768
#define BM 128
#define DS_ELEMS ((size_t)M_TOT * D_)   // 33554432
#define SUS_CAP 2048

typedef _Float16 f16x8 __attribute__((ext_vector_type(8)));
typedef _Float16 f16x4 __attribute__((ext_vector_type(4)));
typedef __bf16  bf16x8 __attribute__((ext_vector_type(8)));
typedef __bf16  bf16x4 __attribute__((ext_vector_type(4)));
typedef float   f32x4  __attribute__((ext_vector_type(4)));

typedef __attribute__((address_space(1))) void gv_t;
typedef __attribute__((address_space(3))) void lv_t;

__device__ __forceinline__ void gl_lds16(const void* g, void* l) {
    __builtin_amdgcn_global_load_lds((gv_t*)g, (lv_t*)l, 16, 0, 0);
}

// ---------------------------------------------------------------------------
// prep: tokens->fp16, W->wT fp16 + wT bf16 hi/lo, zero accumulators+counters
// ---------------------------------------------------------------------------
__global__ __launch_bounds__(256)
void prep(const float* __restrict__ tokens, const float* __restrict__ W,
          _Float16* __restrict__ t_h, _Float16* __restrict__ wT_h,
          __bf16* __restrict__ wT_hi, __bf16* __restrict__ wT_lo,
          float* __restrict__ zbase, float* __restrict__ aux_out)
{
    const int bid = blockIdx.x, tid = threadIdx.x;
    if (bid < 8192) {
        const size_t base = (size_t)bid * 4096 + tid * 4;
        #pragma unroll
        for (int r = 0; r < 4; ++r) {
            size_t idx = base + (size_t)r * 1024;
            float4 v = *(const float4*)&tokens[idx];
            f16x4 h;
            h[0] = (_Float16)v.x; h[1] = (_Float16)v.y;
            h[2] = (_Float16)v.z; h[3] = (_Float16)v.w;
            *(f16x4*)&t_h[idx] = h;
        }
    } else if (bid < 10240) {
        __shared__ float lw[32 * 33];
        const int local = bid - 8192;
        const int k0 = (local & 31) * 32;
        const int n0 = (local >> 5) * 32;
        {
            const int lk = tid >> 3, ln4 = (tid & 7) * 4;
            float4 v = *(const float4*)&W[(size_t)(k0 + lk) * 2048 + n0 + ln4];
            lw[(ln4 + 0) * 33 + lk] = v.x;
            lw[(ln4 + 1) * 33 + lk] = v.y;
            lw[(ln4 + 2) * 33 + lk] = v.z;
            lw[(ln4 + 3) * 33 + lk] = v.w;
        }
        __syncthreads();
        {
            const int ln = tid >> 3, lk4 = (tid & 7) * 4;
            f16x4 h; bf16x4 bh, bl;
            #pragma unroll
            for (int j = 0; j < 4; ++j) {
                float v = lw[ln * 33 + lk4 + j];
                h[j] = (_Float16)v;
                __bf16 b = (__bf16)v;
                bh[j] = b;
                bl[j] = (__bf16)(v - (float)b);
            }
            size_t o = (size_t)(n0 + ln) * 1024 + k0 + lk4;
            *(f16x4*)&wT_h[o]   = h;
            *(bf16x4*)&wT_hi[o] = bh;
            *(bf16x4*)&wT_lo[o] = bl;
        }
    } else {
        const int zb = bid - 10240;                // 0..96
        const int i = zb * 1024 + tid * 4;
        if (i < 98308)
            *(float4*)&zbase[i] = make_float4(0.f, 0.f, 0.f, 0.f);
        if (zb == 0 && tid == 0) *aux_out = 0.f;
    }
}

// ---------------------------------------------------------------------------
// main GEMM: fp16, tile 128 rows x (64 q-cols + 64 k-cols), DOUBLE-BUFFERED
// grid 4096 linear, XCD-swizzled. Epilogue identical to R4.
// ---------------------------------------------------------------------------
__global__ __launch_bounds__(256, 2)
void gemm_cos_f16(const _Float16* __restrict__ t_h, const _Float16* __restrict__ wT_h,
                  float* __restrict__ dotw, float* __restrict__ qn2w,
                  float* __restrict__ ksn2w,
                  float* __restrict__ qrow, float* __restrict__ krow)
{
    __shared__ float smem[8448];        // 33792 B
    // staging: buf0 = bytes [0,16384) [A 8K | B 8K]; buf1 = [16384,32768)
    // epilogue overlay: Ck [128][66] floats = 33792 B
    float* Ck = smem;

    const int bx = blockIdx.x;
    const int tile_n = (bx >> 3) & 15;
    const int tile_m = ((bx >> 7) & 31) + ((bx & 7) << 5);
    const int m0 = tile_m * BM;
    const int n0 = tile_n * 64;
    const int tid  = threadIdx.x;
    const int w    = tid >> 6;
    const int lane = tid & 63;
    const int quad = lane >> 4;
    const int lc   = lane & 15;

    const int wm  = (w & 1) * 64;       // row half
    const int wq0 = (w >> 1) * 32;      // col quarter (within 64)

    const int ia0 = w * 2, ia1 = w * 2 + 1;
    const int st_ch = ((lane & 3) ^ ((lane >> 3) & 3)) * 8;
    const size_t a_g0 = (size_t)(m0 + ia0 * 16 + (lane >> 2)) * 1024 + st_ch;
    const size_t a_g1 = a_g0 + (size_t)16 * 1024;
    const int br0 = ia0 * 16 + (lane >> 2);
    const int br1 = br0 + 16;
    const int gr0 = (br0 < 64) ? (n0 + br0) : (960 + n0 + br0);
    const int gr1 = (br1 < 64) ? (n0 + br1) : (960 + n0 + br1);
    const size_t b_g0 = (size_t)gr0 * 1024 + st_ch;
    const size_t b_g1 = (size_t)gr1 * 1024 + st_ch;

    char* base0 = (char*)smem;
    char* base1 = (char*)smem + 16384;
    const int fr_ch = (quad ^ ((lc >> 1) & 3)) * 8;

    f32x4 accq[4][2] = {};
    f32x4 acck[4][2] = {};

    // prologue: loads for kk=0 into buf0
    gl_lds16(t_h  + a_g0, base0 + ia0 * 1024);
    gl_lds16(t_h  + a_g1, base0 + ia1 * 1024);
    gl_lds16(wT_h + b_g0, base0 + 8192 + ia0 * 1024);
    gl_lds16(wT_h + b_g1, base0 + 8192 + ia1 * 1024);

    for (int kk = 0; kk < 32; ++kk) {
        __syncthreads();    // drains vmcnt: buf[kk&1] ready; buf[(kk+1)&1]
                            // free (all reads of it finished in iter kk-1)
        if (kk < 31) {
            const size_t kb = (size_t)(kk + 1) * 32;
            char* nb = ((kk + 1) & 1) ? base1 : base0;
            gl_lds16(t_h  + a_g0 + kb, nb + ia0 * 1024);
            gl_lds16(t_h  + a_g1 + kb, nb + ia1 * 1024);
            gl_lds16(wT_h + b_g0 + kb, nb + 8192 + ia0 * 1024);
            gl_lds16(wT_h + b_g1 + kb, nb + 8192 + ia1 * 1024);
        }
        const _Float16* As = (const _Float16*)((kk & 1) ? base1 : base0);
        const _Float16* Bs = As + 4096;

        f16x8 af[4], bq[2], bk[2];
        #pragma unroll
        for (int mi = 0; mi < 4; ++mi)
            af[mi] = *(const f16x8*)(As + (wm + mi * 16 + lc) * 32 + fr_ch);
        #pragma unroll
        for (int ni = 0; ni < 2; ++ni) {
            bq[ni] = *(const f16x8*)(Bs + (wq0 + ni * 16 + lc) * 32 + fr_ch);
            bk[ni] = *(const f16x8*)(Bs + (64 + wq0 + ni * 16 + lc) * 32 + fr_ch);
        }
        #pragma unroll
        for (int mi = 0; mi < 4; ++mi) {
            #pragma unroll
            for (int ni = 0; ni < 2; ++ni) {
                accq[mi][ni] = __builtin_amdgcn_mfma_f32_16x16x32_f16(
                    af[mi], bq[ni], accq[mi][ni], 0, 0, 0);
                acck[mi][ni] = __builtin_amdgcn_mfma_f32_16x16x32_f16(
                    af[mi], bk[ni], acck[mi][ni], 0, 0, 0);
            }
        }
    }
    __syncthreads();   // all LDS reads done before the Ck overlay

    // ---- epilogue (identical to R4) ----
    #pragma unroll
    for (int mi = 0; mi < 4; ++mi) {
        #pragma unroll
        for (int reg = 0; reg < 4; ++reg) {
            const int row = wm + mi * 16 + quad * 4 + reg;
            float s = accq[mi][0][reg] * accq[mi][0][reg]
                    + accq[mi][1][reg] * accq[mi][1][reg];
            s += __shfl_xor(s, 1); s += __shfl_xor(s, 2);
            s += __shfl_xor(s, 4); s += __shfl_xor(s, 8);
            if (lc == 0) atomicAdd(&qn2w[m0 + row], s);

            float s2 = acck[mi][0][reg] * acck[mi][0][reg]
                     + acck[mi][1][reg] * acck[mi][1][reg];
            s2 += __shfl_xor(s2, 1); s2 += __shfl_xor(s2, 2);
            s2 += __shfl_xor(s2, 4); s2 += __shfl_xor(s2, 8);
            if (lc == 0 && row < 127) atomicAdd(&ksn2w[m0 + row + 1], s2);
        }
    }

    #pragma unroll
    for (int mi = 0; mi < 4; ++mi)
        #pragma unroll
        for (int ni = 0; ni < 2; ++ni)
            #pragma unroll
            for (int reg = 0; reg < 4; ++reg)
                Ck[(wm + mi * 16 + quad * 4 + reg) * 66 + wq0 + ni * 16 + lc] =
                    acck[mi][ni][reg];
    __syncthreads();

    #pragma unroll
    for (int mi = 0; mi < 4; ++mi) {
        #pragma unroll
        for (int reg = 0; reg < 4; ++reg) {
            const int row = wm + mi * 16 + quad * 4 + reg;
            float d = 0.f;
            if (row >= 1)
                d = accq[mi][0][reg] * Ck[(row - 1) * 66 + wq0 + lc]
                  + accq[mi][1][reg] * Ck[(row - 1) * 66 + wq0 + 16 + lc];
            d += __shfl_xor(d, 1); d += __shfl_xor(d, 2);
            d += __shfl_xor(d, 4); d += __shfl_xor(d, 8);
            if (lc == 0 && row >= 1) atomicAdd(&dotw[m0 + row], d);
        }
    }

    if (wm == 0 && quad == 0) {
        #pragma unroll
        for (int ni = 0; ni < 2; ++ni)
            qrow[(size_t)tile_m * D_ + n0 + wq0 + ni * 16 + lc] = accq[0][ni][0];
    }
    if (wm == 64 && quad == 3) {
        #pragma unroll
        for (int ni = 0; ni < 2; ++ni)
            krow[(size_t)tile_m * D_ + n0 + wq0 + ni * 16 + lc] = acck[3][ni][3];
    }
}

// ---------------------------------------------------------------------------
// fused: boundary dot (t ≡ 0 mod 128) + probs + suspect list (|cos| < 1e-3)
// ---------------------------------------------------------------------------
__global__ __launch_bounds__(256)
void probs_fused(const float* __restrict__ qrow, const float* __restrict__ krow,
                 const float* __restrict__ start_key,
                 const float* __restrict__ dotw, const float* __restrict__ qn2w,
                 const float* __restrict__ ksn2w, float* __restrict__ probsw,
                 int* __restrict__ scount, int* __restrict__ slist)
{
    const int tile = blockIdx.x;
    const int tid = threadIdx.x;
    __shared__ float sd[4], sk[4];

    {
        const float* q  = qrow + (size_t)tile * D_;
        const float* ks = ((tile & 31) == 0) ? start_key
                                             : (krow + (size_t)(tile - 1) * D_);
        float4 qv = *(const float4*)&q[tid * 4];
        float4 kv = *(const float4*)&ks[tid * 4];
        float d  = qv.x * kv.x + qv.y * kv.y + qv.z * kv.z + qv.w * kv.w;
        float k2 = kv.x * kv.x + kv.y * kv.y + kv.z * kv.z + kv.w * kv.w;
        #pragma unroll
        for (int off = 32; off; off >>= 1) {
            d  += __shfl_down(d, off, 64);
            k2 += __shfl_down(k2, off, 64);
        }
        const int lane = tid & 63, wid = tid >> 6;
        if (lane == 0) { sd[wid] = d; sk[wid] = k2; }
    }
    __syncthreads();

    if (tid < BM) {
        const int m = tile * BM + tid;
        float dd = dotw[m], kk = ksn2w[m];
        if (tid == 0) {
            dd = sd[0] + sd[1] + sd[2] + sd[3];
            kk = sk[0] + sk[1] + sk[2] + sk[3];
        }
        float qn = fmaxf(sqrtf(qn2w[m]), 1e-8f);
        float kn = fmaxf(sqrtf(kk), 1e-8f);
        float c = dd / (qn * kn);
        probsw[m] = 0.5f * (1.f - c);
        if (fabsf(c) < 1e-3f) {
            int i = atomicAdd(scount, 1);
            if (i < SUS_CAP) slist[i] = m;
        }
    }
}

// ---------------------------------------------------------------------------
// stage-2 operand build: gather suspect rows (and predecessors) -> bf16 hi/lo
// ---------------------------------------------------------------------------
__global__ __launch_bounds__(256)
void gather_split(const float* __restrict__ tokens, const int* __restrict__ scount,
                  const int* __restrict__ slist,
                  __bf16* __restrict__ As_hi, __bf16* __restrict__ As_lo)
{
    int n = *scount; if (n > SUS_CAP) n = SUS_CAP;
    const int n_up = (n + 127) & ~127;
    const int slot = blockIdx.x;
    const int sl = slot & 2047;
    if (sl >= n_up) return;
    const int tid = threadIdx.x;

    int src = -1;
    if (sl < n) {
        int t = slist[sl];
        if (slot < 2048) src = t;
        else src = ((t & 4095) == 0) ? t : (t - 1);
    }
    bf16x4 h = {}, l = {};
    if (src >= 0) {
        float4 v = *(const float4*)&tokens[(size_t)src * 1024 + tid * 4];
        float vs[4] = {v.x, v.y, v.z, v.w};
        #pragma unroll
        for (int j = 0; j < 4; ++j) {
            __bf16 b = (__bf16)vs[j];
            h[j] = b;
            l[j] = (__bf16)(vs[j] - (float)b);
        }
    }
    size_t o = (size_t)slot * 1024 + tid * 4;
    *(bf16x4*)&As_hi[o] = h;
    *(bf16x4*)&As_lo[o] = l;
}

// ---------------------------------------------------------------------------
// stage-2 GEMM: bf16 3-slab on gathered rows, writes C2 [4096 x 2048] fp32
// ---------------------------------------------------------------------------
__global__ __launch_bounds__(256, 2)
void gemm2(const __bf16* __restrict__ As_hi, const __bf16* __restrict__ As_lo,
           const __bf16* __restrict__ wT_hi, const __bf16* __restrict__ wT_lo,
           const int* __restrict__ scount, float* __restrict__ C2)
{
    int n = *scount; if (n > SUS_CAP) n = SUS_CAP;
    const int tm = blockIdx.y;
    const int local_base = (tm < 16) ? tm * 128 : (tm - 16) * 128;
    if (local_base >= n) return;
    const int m0 = (tm < 16) ? tm * 128 : 2048 + (tm - 16) * 128;

    __shared__ float smem[4096];
    __bf16* As = (__bf16*)smem;
    __bf16* Bs = (__bf16*)smem + 4096;

    const int tile_n = blockIdx.x;
    const int n0 = tile_n * 64;
    const int tid  = threadIdx.x;
    const int w    = tid >> 6;
    const int lane = tid & 63;
    const int quad = lane >> 4;
    const int lc   = lane & 15;
    const int wm  = (w & 1) * 64;
    const int wq0 = (w >> 1) * 32;

    const int ia0 = w * 2, ia1 = w * 2 + 1;
    const int st_ch = ((lane & 3) ^ ((lane >> 3) & 3)) * 8;
    const size_t a_g0 = (size_t)(m0 + ia0 * 16 + (lane >> 2)) * 1024 + st_ch;
    const size_t a_g1 = a_g0 + (size_t)16 * 1024;
    const int br0 = ia0 * 16 + (lane >> 2);
    const int br1 = br0 + 16;
    const int gr0 = (br0 < 64) ? (n0 + br0) : (960 + n0 + br0);
    const int gr1 = (br1 < 64) ? (n0 + br1) : (960 + n0 + br1);
    const size_t b_g0 = (size_t)gr0 * 1024 + st_ch;
    const size_t b_g1 = (size_t)gr1 * 1024 + st_ch;
    char* aL0 = (char*)smem + ia0 * 1024;
    char* aL1 = (char*)smem + ia1 * 1024;
    char* bL0 = (char*)smem + 8192 + ia0 * 1024;
    char* bL1 = (char*)smem + 8192 + ia1 * 1024;
    const int fr_ch = (quad ^ ((lc >> 1) & 3)) * 8;

    f32x4 accq[4][2] = {};
    f32x4 acck[4][2] = {};

    for (int kk = 0; kk < 96; ++kk) {
        const int slab = kk >> 5;
        const size_t kb = (size_t)(kk & 31) * 32;
        const __bf16* Ap = (slab < 2) ? As_hi : As_lo;
        const __bf16* Bp = (slab == 1) ? wT_lo : wT_hi;

        gl_lds16(Ap + a_g0 + kb, aL0);
        gl_lds16(Ap + a_g1 + kb, aL1);
        gl_lds16(Bp + b_g0 + kb, bL0);
        gl_lds16(Bp + b_g1 + kb, bL1);
        __syncthreads();

        bf16x8 af[4], bq[2], bk[2];
        #pragma unroll
        for (int mi = 0; mi < 4; ++mi)
            af[mi] = *(const bf16x8*)(As + (wm + mi * 16 + lc) * 32 + fr_ch);
        #pragma unroll
        for (int ni = 0; ni < 2; ++ni) {
            bq[ni] = *(const bf16x8*)(Bs + (wq0 + ni * 16 + lc) * 32 + fr_ch);
            bk[ni] = *(const bf16x8*)(Bs + (64 + wq0 + ni * 16 + lc) * 32 + fr_ch);
        }
        #pragma unroll
        for (int mi = 0; mi < 4; ++mi) {
            #pragma unroll
            for (int ni = 0; ni < 2; ++ni) {
                accq[mi][ni] = __builtin_amdgcn_mfma_f32_16x16x32_bf16(
                    af[mi], bq[ni], accq[mi][ni], 0, 0, 0);
                acck[mi][ni] = __builtin_amdgcn_mfma_f32_16x16x32_bf16(
                    af[mi], bk[ni], acck[mi][ni], 0, 0, 0);
            }
        }
        __syncthreads();
    }

    #pragma unroll
    for (int mi = 0; mi < 4; ++mi) {
        #pragma unroll
        for (int reg = 0; reg < 4; ++reg) {
            const int row = m0 + wm + mi * 16 + quad * 4 + reg;
            #pragma unroll
            for (int ni = 0; ni < 2; ++ni) {
                C2[(size_t)row * 2048 + n0 + wq0 + ni * 16 + lc] = accq[mi][ni][reg];
                C2[(size_t)row * 2048 + 1024 + n0 + wq0 + ni * 16 + lc] = acck[mi][ni][reg];
            }
        }
    }
}

// ---------------------------------------------------------------------------
// stage-2 resolve: dot/norms from C2; sub-suspects (|cos|<1e-4) -> slist2
// ---------------------------------------------------------------------------
__global__ __launch_bounds__(256)
void dot_fix(const float* __restrict__ C2, const float* __restrict__ start_key,
             const int* __restrict__ scount, const int* __restrict__ slist,
             float* __restrict__ probsw, int* __restrict__ scount2,
             int* __restrict__ slist2)
{
    int n = *scount; if (n > SUS_CAP) n = SUS_CAP;
    const int s = blockIdx.x;
    if (s >= n) return;
    const int tid = threadIdx.x;
    const int t = slist[s];
    const bool st = (t & 4095) == 0;
    const float* q = C2 + (size_t)s * 2048;
    const float* k = st ? start_key : (C2 + (size_t)(2048 + s) * 2048 + 1024);

    float4 qv = *(const float4*)&q[tid * 4];
    float4 kv = *(const float4*)&k[tid * 4];
    float d  = qv.x * kv.x + qv.y * kv.y + qv.z * kv.z + qv.w * kv.w;
    float q2 = qv.x * qv.x + qv.y * qv.y + qv.z * qv.z + qv.w * qv.w;
    float k2 = kv.x * kv.x + kv.y * kv.y + kv.z * kv.z + kv.w * kv.w;
    #pragma unroll
    for (int off = 32; off; off >>= 1) {
        d  += __shfl_down(d, off, 64);
        q2 += __shfl_down(q2, off, 64);
        k2 += __shfl_down(k2, off, 64);
    }
    __shared__ float sd[4], sq[4], sk[4];
    const int lane = tid & 63, wid = tid >> 6;
    if (lane == 0) { sd[wid] = d; sq[wid] = q2; sk[wid] = k2; }
    __syncthreads();
    if (tid == 0) {
        float D  = sd[0] + sd[1] + sd[2] + sd[3];
        float Q2 = sq[0] + sq[1] + sq[2] + sq[3];
        float K2 = sk[0] + sk[1] + sk[2] + sk[3];
        float c = D / (fmaxf(sqrtf(Q2), 1e-8f) * fmaxf(sqrtf(K2), 1e-8f));
        if (fabsf(c) < 1e-4f) {
            int i = atomicAdd(scount2, 1);
            if (i < SUS_CAP) slist2[i] = t;
        } else {
            probsw[t] = 0.5f * (1.f - c);
        }
    }
}

// ---------------------------------------------------------------------------
// stage-3: exact fp32 per-row recompute of sub-suspects
// ---------------------------------------------------------------------------
__global__ __launch_bounds__(256)
void fixup3(const float* __restrict__ tokens, const float* __restrict__ W,
            const float* __restrict__ start_key, const int* __restrict__ scount2,
            const int* __restrict__ slist2, float* __restrict__ probsw)
{
    __shared__ float ta[1024], tb[1024];
    __shared__ float rq[4], rk[4], rd[4];
    const int tid = threadIdx.x;
    int n = *scount2; if (n > SUS_CAP) n = SUS_CAP;

    for (int i = blockIdx.x; i < n; i += gridDim.x) {
        const int t = slist2[i];
        const bool st = (t & 4095) == 0;
        *(float4*)&ta[tid * 4] = *(const float4*)&tokens[(size_t)t * 1024 + tid * 4];
        if (!st)
            *(float4*)&tb[tid * 4] = *(const float4*)&tokens[(size_t)(t - 1) * 1024 + tid * 4];
        __syncthreads();

        float q[4] = {0, 0, 0, 0}, kv[4] = {0, 0, 0, 0};
        if (st) {
            #pragma unroll 4
            for (int k = 0; k < 1024; ++k) {
                float a = ta[k];
                float4 wq = *(const float4*)&W[(size_t)k * 2048 + tid * 4];
                q[0] = fmaf(a, wq.x, q[0]); q[1] = fmaf(a, wq.y, q[1]);
                q[2] = fmaf(a, wq.z, q[2]); q[3] = fmaf(a, wq.w, q[3]);
            }
            float4 sv = *(const float4*)&start_key[tid * 4];
            kv[0] = sv.x; kv[1] = sv.y; kv[2] = sv.z; kv[3] = sv.w;
        } else {
            #pragma unroll 4
            for (int k = 0; k < 1024; ++k) {
                float a = ta[k], b = tb[k];
                float4 wq = *(const float4*)&W[(size_t)k * 2048 + tid * 4];
                float4 wk = *(const float4*)&W[(size_t)k * 2048 + 1024 + tid * 4];
                q[0] = fmaf(a, wq.x, q[0]); q[1] = fmaf(a, wq.y, q[1]);
                q[2] = fmaf(a, wq.z, q[2]); q[3] = fmaf(a, wq.w, q[3]);
                kv[0] = fmaf(b, wk.x, kv[0]); kv[1] = fmaf(b, wk.y, kv[1]);
                kv[2] = fmaf(b, wk.z, kv[2]); kv[3] = fmaf(b, wk.w, kv[3]);
            }
        }
        float q2 = 0, k2 = 0, dd = 0;
        #pragma unroll
        for (int j = 0; j < 4; ++j) {
            q2 += q[j] * q[j]; k2 += kv[j] * kv[j]; dd += q[j] * kv[j];
        }
        #pragma unroll
        for (int off = 32; off; off >>= 1) {
            q2 += __shfl_down(q2, off, 64);
            k2 += __shfl_down(k2, off, 64);
            dd += __shfl_down(dd, off, 64);
        }
        const int lane = tid & 63, wid = tid >> 6;
        if (lane == 0) { rq[wid] = q2; rk[wid] = k2; rd[wid] = dd; }
        __syncthreads();
        if (tid == 0) {
            float Q2 = rq[0] + rq[1] + rq[2] + rq[3];
            float K2 = rk[0] + rk[1] + rk[2] + rk[3];
            float DD = rd[0] + rd[1] + rd[2] + rd[3];
            float qn = fmaxf(sqrtf(Q2), 1e-8f), kn = fmaxf(sqrtf(K2), 1e-8f);
            probsw[t] = 0.5f * (1.f - DD / (qn * kn));
        }
        __syncthreads();
    }
}

// ---------------------------------------------------------------------------
__global__ __launch_bounds__(1024)
void chunk_scan_p(const float* __restrict__ probsw, int* __restrict__ bposw,
                  int* __restrict__ ncw, float* __restrict__ aux_out,
                  float* __restrict__ out_lens)
{
    const int b = blockIdx.x, tid = threadIdx.x;
    const int lane = tid & 63, wid = tid >> 6;
    __shared__ int wcnt[16];
    __shared__ float wsum[16];
    __shared__ int s_nc;
    __shared__ float s_ps;

    const int base = b * L_ + tid * 4;
    float4 pv = *(const float4*)&probsw[base];
    const float p[4] = {pv.x, pv.y, pv.z, pv.w};

    bool mk[4]; int cnt = 0; float psum = 0.f;
    #pragma unroll
    for (int j = 0; j < 4; ++j) {
        mk[j] = (p[j] > 0.5f) || ((tid * 4 + j) == 0);
        cnt += mk[j] ? 1 : 0;
        psum += p[j];
    }
    int inc = cnt;
    #pragma unroll
    for (int off = 1; off < 64; off <<= 1) {
        int nn = __shfl_up(inc, off, 64);
        if (lane >= off) inc += nn;
    }
    float ps = psum;
    #pragma unroll
    for (int off = 32; off; off >>= 1) ps += __shfl_down(ps, off, 64);
    if (lane == 63) wcnt[wid] = inc;
    if (lane == 0)  wsum[wid] = ps;
    __syncthreads();
    if (tid == 0) {
        int run = 0; float tt = 0.f;
        for (int i = 0; i < 16; ++i) { int c = wcnt[i]; wcnt[i] = run; run += c; tt += wsum[i]; }
        s_nc = run; s_ps = tt;
    }
    __syncthreads();
    const int nc = s_nc;
    int idx = wcnt[wid] + (inc - cnt);
    #pragma unroll
    for (int j = 0; j < 4; ++j)
        if (mk[j]) { bposw[b * L_ + idx] = tid * 4 + j; ++idx; }
    if (tid == 0) {
        ncw[b] = nc;
        float G  = s_ps * (1.f / L_);
        float Fm = (float)nc * (1.f / L_);
        atomicAdd(aux_out, 0.0045f * (5.f * Fm * G + (1.f - Fm) * (1.f - G)));
    }
    __syncthreads();
    #pragma unroll
    for (int j = 0; j < 4; ++j) {
        int i = tid * 4 + j;
        float len = 0.f;
        if (i < nc) {
            int pi  = bposw[b * L_ + i];
            int nxt = (i + 1 < nc) ? bposw[b * L_ + i + 1] : L_;
            len = (float)(nxt - pi);
        }
        out_lens[b * L_ + i] = len;
    }
}

__global__ __launch_bounds__(256)
void gather_ds(const float* __restrict__ tokens, const float* __restrict__ probsw,
               const int* __restrict__ bposw, const int* __restrict__ ncw,
               float* __restrict__ out)
{
    const int row = blockIdx.x;
    const int b = row >> 12, i = row & 4095;
    const int nc = ncw[b];
    float4 v = make_float4(0.f, 0.f, 0.f, 0.f);
    if (i < nc) {
        const int t = bposw[b * L_ + i];
        const float pv = probsw[b * L_ + t];
        float4 tv = *(const float4*)&tokens[((size_t)(b << 12) + t) * D_ + threadIdx.x * 4];
        v = make_float4(tv.x * pv, tv.y * pv, tv.z * pv, tv.w * pv);
    }
    *(float4*)&out[(size_t)row * D_ + threadIdx.x * 4] = v;
}

// ===========================================================================
extern "C" void kernel_launch(void* const* d_in, const int* in_sizes, int n_in,
                              void* d_out, int out_size, void* d_ws, size_t ws_size,
                              hipStream_t stream)
{
    const float* tokens    = (const float*)d_in[0];
    const float* W_qk      = (const float*)d_in[1];
    const float* start_key = (const float*)d_in[2];
    float* out = (float*)d_out;
    float* lens_out = out + DS_ELEMS;
    float* aux_out  = out + DS_ELEMS + M_TOT;

    // ws layout (floats) — total 1740812 floats ≈ 6.96 MB
    float* wf = (float*)d_ws;
    float* dotw    = wf;                       // 32768
    float* qn2w    = wf + 32768;               // 32768
    float* ksn2w   = wf + 65536;               // 32768
    int*   scount  = (int*)(wf + 98304);       // 1
    int*   scount2 = (int*)(wf + 98305);       // 1 (+2 pad)
    float* probsw  = wf + 98308;               // 32768
    int*   bposw   = (int*)(wf + 131076);      // 32768
    int*   ncw     = (int*)(wf + 163844);      // 8
    int*   slist   = (int*)(wf + 163852);      // 2048
    int*   slist2  = (int*)(wf + 165900);      // 2048
    float* qrow    = wf + 167948;              // 262144
    float* krow    = wf + 430092;              // 262144
    _Float16* wT_h = (_Float16*)(wf + 692236); // 2097152 halves

    // d_out scratch (overwritten by gather_ds at the end)
    _Float16* t_h  = (_Float16*)out;                   // 33554432 halves
    __bf16* As_hi  = (__bf16*)(out + 16777216);        // 4096x1024
    __bf16* As_lo  = (__bf16*)(out + 18874368);
    float*  C2     = out + 20971520;                   // 4096x2048 fp32
    __bf16* wT_hi  = (__bf16*)(out + 29360128);        // 2048x1024
    __bf16* wT_lo  = (__bf16*)(out + 30408704);

    prep<<<10337, 256, 0, stream>>>(tokens, W_qk, t_h, wT_h, wT_hi, wT_lo,
                                    wf, aux_out);
    gemm_cos_f16<<<4096, 256, 0, stream>>>(t_h, wT_h, dotw, qn2w, ksn2w,
                                           qrow, krow);
    probs_fused<<<256, 256, 0, stream>>>(qrow, krow, start_key, dotw, qn2w,
                                         ksn2w, probsw, scount, slist);
    gather_split<<<4096, 256, 0, stream>>>(tokens, scount, slist, As_hi, As_lo);
    gemm2<<<dim3(16, 32), 256, 0, stream>>>(As_hi, As_lo, wT_hi, wT_lo,
                                            scount, C2);
    dot_fix<<<2048, 256, 0, stream>>>(C2, start_key, scount, slist, probsw,
                                      scount2, slist2);
    fixup3<<<128, 256, 0, stream>>>(tokens, W_qk, start_key, scount2, slist2,
                                    probsw);
    chunk_scan_p<<<B_, 1024, 0, stream>>>(probsw, bposw, ncw, aux_out, lens_out);
    gather_ds<<<M_TOT, 256, 0, stream>>>(tokens, probsw, bposw, ncw, out);
}